// Round 5
// baseline (124421.228 us; speedup 1.0000x reference)
//
#include <hip/hip_runtime.h>
#include <math.h>

#define NP 16384
#define SP 4096
#define CINCH 32
#define CO 64
#define KK 16
#define GRIDC 16          // cells per dim
#define NCELLS 4096       // 16^3

// ---------------- helpers ----------------
__device__ __forceinline__ float waveGemm64(float xv, const float* __restrict__ wl, int c) {
  float a0=0.f,a1=0.f,a2=0.f,a3=0.f;
  #pragma unroll
  for (int k=0;k<64;k+=4){
    a0 = fmaf(__shfl(xv,k  ), wl[(k  )*CO+c], a0);
    a1 = fmaf(__shfl(xv,k+1), wl[(k+1)*CO+c], a1);
    a2 = fmaf(__shfl(xv,k+2), wl[(k+2)*CO+c], a2);
    a3 = fmaf(__shfl(xv,k+3), wl[(k+3)*CO+c], a3);
  }
  return (a0+a1)+(a2+a3);
}

__device__ __forceinline__ int morton12(int x,int y,int z){
  int m=0;
  #pragma unroll
  for (int b=0;b<4;b++){
    m |= ((x>>b)&1)<<(3*b) | ((y>>b)&1)<<(3*b+1) | ((z>>b)&1)<<(3*b+2);
  }
  return m;
}

__device__ __forceinline__ unsigned long long shflx64(unsigned long long v, int m){
  int lo = __shfl_xor((int)(unsigned)(v & 0xffffffffULL), m);
  int hi = __shfl_xor((int)(unsigned)(v >> 32), m);
  return ((unsigned long long)(unsigned)hi << 32) | (unsigned)lo;
}

// ---------------- pts4: pack xyz + |p|^2 ----------------
__global__ __launch_bounds__(256) void k_pts4(const float* __restrict__ pts, float4* __restrict__ pts4) {
  int i = blockIdx.x*256 + threadIdx.x;
  float x = pts[3*i], y = pts[3*i+1], z = pts[3*i+2];
  pts4[i] = make_float4(x,y,z, x*x + y*y + z*z);
}

// ---------------- QKV projections ----------------
__global__ __launch_bounds__(256) void k_qkv(const float* __restrict__ feat,
    const float* __restrict__ Wq, const float* __restrict__ Wk, const float* __restrict__ Wv,
    float* __restrict__ fq, float* __restrict__ fk, float* __restrict__ fv) {
  int r = threadIdx.x >> 6, c = threadIdx.x & 63;
  int row = blockIdx.x*4 + r;
  const float* f = feat + row*CINCH;
  float aq=0.f, ak=0.f, av=0.f;
  #pragma unroll
  for (int k=0;k<CINCH;k++){
    float fe = f[k];
    aq = fmaf(fe, Wq[k*CO+c], aq);
    ak = fmaf(fe, Wk[k*CO+c], ak);
    av = fmaf(fe, Wv[k*CO+c], av);
  }
  fq[row*CO+c]=aq; fk[row*CO+c]=ak; fv[row*CO+c]=av;
}

// ---------------- KNN16 partial: per-part register top-16 (sorted-shift) ----------------
#define KTS 2048
__global__ __launch_bounds__(256,4) void k_knn16p(const float4* __restrict__ qp,
    const float4* __restrict__ cp, int clen,
    float* __restrict__ psv, int* __restrict__ psi) {
  __shared__ float4 tile[KTS];
  int q = blockIdx.x*256 + threadIdx.x;
  int part = blockIdx.y;
  int nspl = gridDim.y;
  int c0 = part*clen;
  float4 tq = qp[q];
  float qx=tq.x, qy=tq.y, qz=tq.z;
  float v[KK]; int id[KK];
  #pragma unroll
  for (int k=0;k<KK;k++){ v[k]=3.4e38f; id[k]=0x7fffffff; }
  for (int base=c0; base<c0+clen; base+=KTS){
    __syncthreads();
    for (int tt=threadIdx.x;tt<KTS;tt+=256) tile[tt]=cp[base+tt];
    __syncthreads();
    for (int j=0;j<KTS;j++){
      float4 cpt=tile[j];
      float dot = qx*cpt.x + qy*cpt.y + qz*cpt.z;
      float s = fmaf(-2.f,dot,cpt.w);
      if (s < v[KK-1]) {             // strict: equal value stays out (earlier index wins)
        int gj = base+j;
        #pragma unroll
        for (int k=KK-1;k>=1;--k){
          bool sh = s < v[k-1];
          bool pl = s < v[k];        // old v[k]
          float nv = sh ? v[k-1] : (pl ? s  : v[k]);
          int   ni = sh ? id[k-1] : (pl ? gj : id[k]);
          v[k]=nv; id[k]=ni;
        }
        if (s < v[0]){ v[0]=s; id[0]=gj; }
      }
    }
  }
  size_t o = ((size_t)q*nspl + part)*KK;
  #pragma unroll
  for (int k=0;k<KK;k++){ psv[o+k]=v[k]; psi[o+k]=id[k]; }
}

// ---------------- merge NS sorted 16-lists -> top 16 (lexicographic (v,idx)) ----------------
template<int NS>
__global__ __launch_bounds__(256,4) void k_merge(const float* __restrict__ psv,
    const int* __restrict__ psi, int* __restrict__ oidx) {
  int q = blockIdx.x*256 + threadIdx.x;
  const float* pv = psv + (size_t)q*NS*KK;
  const int*   pi = psi + (size_t)q*NS*KK;
  int pos[NS]; float hv[NS]; int hi[NS];
  #pragma unroll
  for (int p=0;p<NS;p++){ pos[p]=0; hv[p]=pv[p*KK]; hi[p]=pi[p*KK]; }
  #pragma unroll
  for (int k=0;k<KK;k++){
    int best=0; float bv=hv[0]; int bi=hi[0];
    #pragma unroll
    for (int p=1;p<NS;p++){
      bool g=(hv[p]<bv)||((hv[p]==bv)&&(hi[p]<bi));
      if (g){ bv=hv[p]; bi=hi[p]; best=p; }
    }
    oidx[q*KK+k]=bi;
    #pragma unroll
    for (int p=0;p<NS;p++) if (best==p){
      pos[p]++;
      bool ok = pos[p]<KK;
      hv[p] = ok ? pv[p*KK+pos[p]] : 3.4e38f;
      hi[p] = ok ? pi[p*KK+pos[p]] : 0x7fffffff;
    }
  }
}

// ---------------- rel = p_i - p_knn ; y = rel @ Wp1 ; stats ----------------
__global__ __launch_bounds__(256) void k_rel(const float4* __restrict__ pts4, const int* __restrict__ kidx,
    const float* __restrict__ Wp1, float* __restrict__ y, float* __restrict__ st) {
  int r = blockIdx.x*256 + threadIdx.x;
  int i = r>>4;
  int j = kidx[r];
  float4 pi=pts4[i], pj=pts4[j];
  float rx=pi.x-pj.x, ry=pi.y-pj.y, rz=pi.z-pj.z;
  float s[3], sq[3];
  #pragma unroll
  for (int c=0;c<3;c++){
    float yc = rx*Wp1[c] + ry*Wp1[3+c] + rz*Wp1[6+c];
    y[r*3+c]=yc; s[c]=yc; sq[c]=yc*yc;
  }
  #pragma unroll
  for (int c=0;c<3;c++){
    float a=s[c], b=sq[c];
    #pragma unroll
    for (int o=32;o;o>>=1){ a+=__shfl_down(a,o); b+=__shfl_down(b,o); }
    if ((threadIdx.x&63)==0){ atomicAdd(&st[c],a); atomicAdd(&st[3+c],b); }
  }
}

// ---------------- yn = relu(bn(y)) ----------------
__global__ __launch_bounds__(256) void k_yn(const float* __restrict__ y, const float* __restrict__ st,
    const float* __restrict__ gp, const float* __restrict__ bp, float* __restrict__ yn) {
  int r = blockIdx.x*256 + threadIdx.x;
  const float invn = 1.f/(float)(NP*KK);
  #pragma unroll
  for (int c=0;c<3;c++){
    float m = st[c]*invn;
    float var = st[3+c]*invn - m*m;
    float rs = 1.f/sqrtf(var+1e-5f);
    float t = (y[r*3+c]-m)*rs;
    t = fmaf(t, gp[c], bp[c]);
    yn[r*3+c] = fmaxf(t,0.f);
  }
}

// ---------------- stats of x = fq - fk[knn] + rpe ----------------
__global__ __launch_bounds__(256) void k_xstats(const float* __restrict__ fq, const float* __restrict__ fk,
    const int* __restrict__ kidx, const float* __restrict__ yn, const float* __restrict__ Wp2,
    float* __restrict__ st) {
  __shared__ float red[2][4][64];
  int w=threadIdx.x>>6, c=threadIdx.x&63;
  float w0=Wp2[c], w1=Wp2[64+c], w2=Wp2[128+c];
  float s=0.f,sq=0.f;
  int row0 = blockIdx.x*256 + w*64;
  for (int t=0;t<64;t++){
    int r=row0+t; int p=r>>4; int j=kidx[r];
    float y0=yn[r*3], y1=yn[r*3+1], y2=yn[r*3+2];
    float x = fq[p*CO+c]-fk[j*CO+c]+(y0*w0+y1*w1+y2*w2);
    s+=x; sq=fmaf(x,x,sq);
  }
  red[0][w][c]=s; red[1][w][c]=sq;
  __syncthreads();
  if (w==0){
    float a=red[0][0][c]+red[0][1][c]+red[0][2][c]+red[0][3][c];
    float b=red[1][0][c]+red[1][1][c]+red[1][2][c]+red[1][3][c];
    atomicAdd(&st[c],a); atomicAdd(&st[64+c],b);
  }
}

// ---------------- stats of x1 = relu(bn1(x)) @ Wa1 ----------------
__global__ __launch_bounds__(256) void k_x1stats(const float* __restrict__ fq,const float* __restrict__ fk,
    const int* __restrict__ kidx, const float* __restrict__ yn, const float* __restrict__ Wp2,
    const float* __restrict__ Wa1, const float* __restrict__ ga1, const float* __restrict__ ba1,
    const float* __restrict__ stx, float* __restrict__ st1) {
  __shared__ float wa1[4096];
  __shared__ float red[2][4][64];
  for (int t=threadIdx.x;t<4096;t+=256) wa1[t]=Wa1[t];
  int w=threadIdx.x>>6, c=threadIdx.x&63;
  const float invn=1.f/(float)(NP*KK);
  float m1=stx[c]*invn; float vv=stx[64+c]*invn-m1*m1; float rs1=1.f/sqrtf(vv+1e-5f);
  float g1=ga1[c], bb1=ba1[c];
  float w0=Wp2[c],w1=Wp2[64+c],w2=Wp2[128+c];
  __syncthreads();
  float s=0.f,sq=0.f;
  int row0 = blockIdx.x*128 + w*32;
  for (int t=0;t<32;t++){
    int r=row0+t; int p=r>>4; int j=kidx[r];
    float y0=yn[r*3],y1=yn[r*3+1],y2=yn[r*3+2];
    float x = fq[p*CO+c]-fk[j*CO+c]+(y0*w0+y1*w1+y2*w2);
    float tt=(x-m1)*rs1; tt=fmaxf(fmaf(tt,g1,bb1),0.f);
    float x1 = waveGemm64(tt, wa1, c);
    s += x1; sq = fmaf(x1,x1,sq);
  }
  red[0][w][c]=s; red[1][w][c]=sq;
  __syncthreads();
  if (w==0){
    float a=red[0][0][c]+red[0][1][c]+red[0][2][c]+red[0][3][c];
    float b=red[1][0][c]+red[1][1][c]+red[1][2][c]+red[1][3][c];
    atomicAdd(&st1[c],a); atomicAdd(&st1[64+c],b);
  }
}

// ---------------- attention: x2, softmax over K, skip ----------------
__global__ __launch_bounds__(256) void k_attn(const float* __restrict__ fq,const float* __restrict__ fk,
    const float* __restrict__ fv,const int* __restrict__ kidx,const float* __restrict__ yn,
    const float* __restrict__ Wp2,const float* __restrict__ Wa1,const float* __restrict__ Wa2,
    const float* __restrict__ ga1,const float* __restrict__ ba1,const float* __restrict__ ga2,
    const float* __restrict__ ba2,const float* __restrict__ b_a2,
    const float* __restrict__ stx,const float* __restrict__ st1, float* __restrict__ skip) {
  __shared__ float wa1[4096], wa2[4096];
  __shared__ float sc[4][16][64];
  for (int t=threadIdx.x;t<4096;t+=256){ wa1[t]=Wa1[t]; wa2[t]=Wa2[t]; }
  int w=threadIdx.x>>6, c=threadIdx.x&63;
  int p = blockIdx.x*4 + w;
  const float invn = 1.f/(float)(NP*KK);
  float m1=stx[c]*invn; float va=stx[64+c]*invn-m1*m1; float rs1=1.f/sqrtf(va+1e-5f);
  float m2=st1[c]*invn; float vb=st1[64+c]*invn-m2*m2; float rs2=1.f/sqrtf(vb+1e-5f);
  float g1=ga1[c], bb1=ba1[c], g2=ga2[c], bb2=ba2[c], bc=b_a2[c];
  float w0=Wp2[c], w1=Wp2[64+c], w2=Wp2[128+c];
  float fqv = fq[p*CO+c];
  __syncthreads();
  for (int k=0;k<16;k++){
    int r=p*16+k; int j=kidx[r];
    float y0=yn[r*3],y1=yn[r*3+1],y2=yn[r*3+2];
    float x = fqv - fk[j*CO+c] + (y0*w0+y1*w1+y2*w2);
    float t1 = (x-m1)*rs1; t1 = fmaxf(fmaf(t1,g1,bb1),0.f);
    float x1 = waveGemm64(t1, wa1, c);
    float t2 = (x1-m2)*rs2; t2 = fmaxf(fmaf(t2,g2,bb2),0.f);
    float x2 = waveGemm64(t2, wa2, c) + bc;
    sc[w][k][c] = x2;
  }
  float mx = sc[w][0][c];
  #pragma unroll
  for (int k=1;k<16;k++) mx = fmaxf(mx, sc[w][k][c]);
  float sum=0.f;
  for (int k=0;k<16;k++){ float e=expf(sc[w][k][c]-mx); sc[w][k][c]=e; sum+=e; }
  float acc=0.f;
  for (int k=0;k<16;k++){
    int r=p*16+k; int j=kidx[r];
    float y0=yn[r*3],y1=yn[r*3+1],y2=yn[r*3+2];
    float rpe = y0*w0+y1*w1+y2*w2;
    acc = fmaf(sc[w][k][c], fv[j*CO+c]+rpe, acc);
  }
  skip[p*CO+c] = acc/sum;
}

// ---------------- bbox reduce ----------------
__global__ __launch_bounds__(1024) void k_bbox(const float4* __restrict__ pts4, float* __restrict__ bbox) {
  __shared__ float red[6][16];
  int t = threadIdx.x;
  float mnx=3e38f,mny=3e38f,mnz=3e38f,mxx=-3e38f,mxy=-3e38f,mxz=-3e38f;
  for (int i=t;i<NP;i+=1024){
    float4 p = pts4[i];
    mnx=fminf(mnx,p.x); mny=fminf(mny,p.y); mnz=fminf(mnz,p.z);
    mxx=fmaxf(mxx,p.x); mxy=fmaxf(mxy,p.y); mxz=fmaxf(mxz,p.z);
  }
  #pragma unroll
  for (int o=1;o<64;o<<=1){
    mnx=fminf(mnx,__shfl_xor(mnx,o)); mny=fminf(mny,__shfl_xor(mny,o)); mnz=fminf(mnz,__shfl_xor(mnz,o));
    mxx=fmaxf(mxx,__shfl_xor(mxx,o)); mxy=fmaxf(mxy,__shfl_xor(mxy,o)); mxz=fmaxf(mxz,__shfl_xor(mxz,o));
  }
  if ((t&63)==0){
    int w=t>>6;
    red[0][w]=mnx; red[1][w]=mny; red[2][w]=mnz; red[3][w]=mxx; red[4][w]=mxy; red[5][w]=mxz;
  }
  __syncthreads();
  if (t==0){
    float a0=red[0][0],a1=red[1][0],a2=red[2][0],a3=red[3][0],a4=red[4][0],a5=red[5][0];
    for (int w=1;w<16;w++){
      a0=fminf(a0,red[0][w]); a1=fminf(a1,red[1][w]); a2=fminf(a2,red[2][w]);
      a3=fmaxf(a3,red[3][w]); a4=fmaxf(a4,red[4][w]); a5=fmaxf(a5,red[5][w]);
    }
    bbox[0]=a0; bbox[1]=a1; bbox[2]=a2; bbox[3]=a3; bbox[4]=a4; bbox[5]=a5;
  }
}

// ---------------- cell histogram ----------------
__global__ __launch_bounds__(256) void k_cellhist(const float4* __restrict__ pts4,
    const float* __restrict__ bbox, int* __restrict__ hist) {
  int i = blockIdx.x*256 + threadIdx.x;
  float4 p = pts4[i];
  float sx=(float)GRIDC/(bbox[3]-bbox[0]+1e-6f);
  float sy=(float)GRIDC/(bbox[4]-bbox[1]+1e-6f);
  float sz=(float)GRIDC/(bbox[5]-bbox[2]+1e-6f);
  int cx=min(GRIDC-1,max(0,(int)((p.x-bbox[0])*sx)));
  int cy=min(GRIDC-1,max(0,(int)((p.y-bbox[1])*sy)));
  int cz=min(GRIDC-1,max(0,(int)((p.z-bbox[2])*sz)));
  atomicAdd(&hist[morton12(cx,cy,cz)],1);
}

// ---------------- exclusive scan of hist[4096] ----------------
__global__ __launch_bounds__(1024) void k_scan(const int* __restrict__ hist, int* __restrict__ cellStart) {
  __shared__ int wsum[16];
  int t = threadIdx.x;
  int h0=hist[4*t], h1=hist[4*t+1], h2=hist[4*t+2], h3=hist[4*t+3];
  int T = h0+h1+h2+h3;
  int incl = T;
  #pragma unroll
  for (int o=1;o<64;o<<=1){
    int n = __shfl_up(incl,o);
    if ((t&63)>=o) incl += n;
  }
  if ((t&63)==63) wsum[t>>6]=incl;
  __syncthreads();
  int woff=0;
  for (int i=0;i<(t>>6);i++) woff += wsum[i];
  int excl = woff + incl - T;
  cellStart[4*t]=excl; cellStart[4*t+1]=excl+h0; cellStart[4*t+2]=excl+h0+h1; cellStart[4*t+3]=excl+h0+h1+h2;
}

// ---------------- scatter into Morton order, TRANSPOSED layout for FPS ----------------
// slot pos (Morton rank) -> lane = pos>>8 (owner), rem = pos&255;
// cT[rem*64 + lane] = (x,y,z, oid_bits). Lane's point (c,j) = cT[(c*32+j)*64+lane].
__global__ __launch_bounds__(256) void k_scatter(const float4* __restrict__ pts4,
    const float* __restrict__ bbox, const int* __restrict__ cellStart, int* __restrict__ cursor,
    float4* __restrict__ cT) {
  int i = blockIdx.x*256 + threadIdx.x;
  float4 p = pts4[i];
  float sx=(float)GRIDC/(bbox[3]-bbox[0]+1e-6f);
  float sy=(float)GRIDC/(bbox[4]-bbox[1]+1e-6f);
  float sz=(float)GRIDC/(bbox[5]-bbox[2]+1e-6f);
  int cx=min(GRIDC-1,max(0,(int)((p.x-bbox[0])*sx)));
  int cy=min(GRIDC-1,max(0,(int)((p.y-bbox[1])*sy)));
  int cz=min(GRIDC-1,max(0,(int)((p.z-bbox[2])*sz)));
  int cell = morton12(cx,cy,cz);
  int pos = cellStart[cell] + atomicAdd(&cursor[cell],1);
  int lane = pos>>8, rem = pos&255;
  cT[rem*64+lane] = make_float4(p.x,p.y,p.z,__int_as_float(i));
}

// ---------------- FPS v5: SINGLE WAVE, 2-level exact pruning, u64-key reduce ----------------
// 64 lanes x 256 pts (8 subclusters of 32). dmin in LDS (lane-minor float4,
// conflict-free). No barriers. Reduce = packed u64 key (value|inv_oid|lane),
// fan-in-4 butterfly (3 dependent shuffle stages) + winner coord broadcast
// (1 stage). Skip sub iff D2 >= ((r+sqrt(bv))*margins)^2 -> provable fmin
// no-op, cached (bv,oid,coords) stay exact. Active-path d matches reference
// assoc with contract off -> bit-exact.
__global__ __launch_bounds__(64,1) void k_fps(const float4* __restrict__ pts4,
    const float4* __restrict__ cT, int* __restrict__ sidx) {
  #pragma clang fp contract(off)
  __shared__ float4 dm4[4096];      // 64KB: [(c*8+jq)*64+lane] -> 4 dmins
  const int lane = threadIdx.x;
  float scx[8],scy[8],scz[8],srad[8],sthr[8],sbv[8],sax[8],say[8],saz[8];
  int soid[8];
  float Lmnx=3e38f,Lmny=3e38f,Lmnz=3e38f,Lmxx=-3e38f,Lmxy=-3e38f,Lmxz=-3e38f;
  #pragma unroll
  for (int c=0;c<8;c++){
    float mnx=3e38f,mny=3e38f,mnz=3e38f,mxx=-3e38f,mxy=-3e38f,mxz=-3e38f;
    for (int j=0;j<32;j++){
      float4 p = cT[(c*32+j)*64+lane];
      mnx=fminf(mnx,p.x); mny=fminf(mny,p.y); mnz=fminf(mnz,p.z);
      mxx=fmaxf(mxx,p.x); mxy=fmaxf(mxy,p.y); mxz=fmaxf(mxz,p.z);
    }
    float ccx=0.5f*(mnx+mxx), ccy=0.5f*(mny+mxy), ccz=0.5f*(mnz+mxz);
    float r2=0.f; int mo=0x7fffffff; float mxc=0.f,myc=0.f,mzc=0.f;
    for (int j=0;j<32;j++){
      float4 p = cT[(c*32+j)*64+lane];
      float dx=p.x-ccx, dy=p.y-ccy, dz=p.z-ccz;
      r2=fmaxf(r2,(dx*dx+dy*dy)+dz*dz);
      int o=__float_as_int(p.w);
      bool g = o<mo;
      mo=g?o:mo; mxc=g?p.x:mxc; myc=g?p.y:myc; mzc=g?p.z:mzc;
    }
    scx[c]=ccx; scy[c]=ccy; scz[c]=ccz;
    srad[c]=sqrtf(r2)*1.00002f+1e-6f;
    sthr[c]=1e30f; sbv[c]=1e10f; soid[c]=mo; sax[c]=mxc; say[c]=myc; saz[c]=mzc;
    Lmnx=fminf(Lmnx,mnx); Lmny=fminf(Lmny,mny); Lmnz=fminf(Lmnz,mnz);
    Lmxx=fmaxf(Lmxx,mxx); Lmxy=fmaxf(Lmxy,mxy); Lmxz=fmaxf(Lmxz,mxz);
  }
  float Lcx=0.5f*(Lmnx+Lmxx), Lcy=0.5f*(Lmny+Lmxy), Lcz=0.5f*(Lmnz+Lmxz);
  float LrS=0.f;
  #pragma unroll
  for (int c=0;c<8;c++){
    float dx=scx[c]-Lcx, dy=scy[c]-Lcy, dz=scz[c]-Lcz;
    LrS = fmaxf(LrS, sqrtf((dx*dx+dy*dy)+dz*dz)+srad[c]);
  }
  LrS = LrS*1.00002f+1e-6f;
  float Lthr=1e30f;
  float lbv=1e10f; int loid=soid[0]; float lx=sax[0], ly=say[0], lz=saz[0];
  #pragma unroll
  for (int c=1;c<8;c++){
    bool g=soid[c]<loid;
    loid=g?soid[c]:loid; lx=g?sax[c]:lx; ly=g?say[c]:ly; lz=g?saz[c]:lz;
  }
  {
    float4 iv = make_float4(1e10f,1e10f,1e10f,1e10f);
    for (int q=0;q<64;q++) dm4[q*64+lane]=iv;
  }
  int far_oid=0;
  float4 f0 = pts4[0];
  float fx=f0.x, fy=f0.y, fz=f0.z;

  for (int s=0;s<SP;s++){
    if (lane==0) sidx[s]=far_oid;
    float DxL=fx-Lcx, DyL=fy-Lcy, DzL=fz-Lcz;
    float D2L=(DxL*DxL+DyL*DyL)+DzL*DzL;
    if (D2L < Lthr){
      bool anych=false;
      #pragma unroll
      for (int c=0;c<8;c++){
        float dxc=fx-scx[c], dyc=fy-scy[c], dzc=fz-scz[c];
        float D2=(dxc*dxc+dyc*dyc)+dzc*dzc;
        if (D2 < sthr[c]){
          anych=true;
          float nbv=-1.f; int noid=0x7fffffff; float nax=0.f,nay=0.f,naz=0.f;
          for (int jq=0;jq<8;jq++){
            int qi=(c*8+jq)*64+lane;
            int pbase=(c*32+jq*4)*64+lane;
            float4 dmv = dm4[qi];
            float4 p0 = cT[pbase];
            float4 p1 = cT[pbase+64];
            float4 p2 = cT[pbase+128];
            float4 p3 = cT[pbase+192];
            float d0,d1,d2,d3;
            { float dx=p0.x-fx,dy=p0.y-fy,dz=p0.z-fz; d0=(dx*dx+dy*dy)+dz*dz; }
            { float dx=p1.x-fx,dy=p1.y-fy,dz=p1.z-fz; d1=(dx*dx+dy*dy)+dz*dz; }
            { float dx=p2.x-fx,dy=p2.y-fy,dz=p2.z-fz; d2=(dx*dx+dy*dy)+dz*dz; }
            { float dx=p3.x-fx,dy=p3.y-fy,dz=p3.z-fz; d3=(dx*dx+dy*dy)+dz*dz; }
            dmv.x=fminf(dmv.x,d0); dmv.y=fminf(dmv.y,d1);
            dmv.z=fminf(dmv.z,d2); dmv.w=fminf(dmv.w,d3);
            dm4[qi]=dmv;
            { int o=__float_as_int(p0.w); bool g=(dmv.x>nbv)||((dmv.x==nbv)&&(o<noid));
              nbv=g?dmv.x:nbv; noid=g?o:noid; nax=g?p0.x:nax; nay=g?p0.y:nay; naz=g?p0.z:naz; }
            { int o=__float_as_int(p1.w); bool g=(dmv.y>nbv)||((dmv.y==nbv)&&(o<noid));
              nbv=g?dmv.y:nbv; noid=g?o:noid; nax=g?p1.x:nax; nay=g?p1.y:nay; naz=g?p1.z:naz; }
            { int o=__float_as_int(p2.w); bool g=(dmv.z>nbv)||((dmv.z==nbv)&&(o<noid));
              nbv=g?dmv.z:nbv; noid=g?o:noid; nax=g?p2.x:nax; nay=g?p2.y:nay; naz=g?p2.z:naz; }
            { int o=__float_as_int(p3.w); bool g=(dmv.w>nbv)||((dmv.w==nbv)&&(o<noid));
              nbv=g?dmv.w:nbv; noid=g?o:noid; nax=g?p3.x:nax; nay=g?p3.y:nay; naz=g?p3.z:naz; }
          }
          sbv[c]=nbv; soid[c]=noid; sax[c]=nax; say[c]=nay; saz[c]=naz;
          float sb=sqrtf(nbv)*1.00002f;
          float tq=srad[c]+sb; sthr[c]=(tq*tq)*1.002f;
        }
      }
      if (anych){
        float nb=sbv[0]; int no=soid[0]; float nx=sax[0],ny=say[0],nz=saz[0];
        #pragma unroll
        for (int c=1;c<8;c++){
          bool g=(sbv[c]>nb)||((sbv[c]==nb)&&(soid[c]<no));
          nb=g?sbv[c]:nb; no=g?soid[c]:no; nx=g?sax[c]:nx; ny=g?say[c]:ny; nz=g?saz[c]:nz;
        }
        lbv=nb; loid=no; lx=nx; ly=ny; lz=nz;
        float sb=sqrtf(lbv)*1.00002f;
        float tq=LrS+sb; Lthr=(tq*tq)*1.002f;
      }
    }
    // packed-key reduce: value (positive-float bits, monotone) | inv_oid | lane
    unsigned long long key = ((unsigned long long)__float_as_uint(lbv)<<32)
                           | ((unsigned long long)(unsigned)(16383-loid)<<6)
                           | (unsigned long long)(unsigned)lane;
    unsigned long long a,b,cc;
    a=shflx64(key,1); b=shflx64(key,2); cc=shflx64(key,3);
    key = a>key?a:key; key = b>key?b:key; key = cc>key?cc:key;
    a=shflx64(key,4); b=shflx64(key,8); cc=shflx64(key,12);
    key = a>key?a:key; key = b>key?b:key; key = cc>key?cc:key;
    a=shflx64(key,16); b=shflx64(key,32); cc=shflx64(key,48);
    key = a>key?a:key; key = b>key?b:key; key = cc>key?cc:key;
    int wl = (int)(key & 63ULL);
    far_oid = 16383 - (int)((key>>6) & 0x3FFFULL);
    fx=__shfl(lx,wl); fy=__shfl(ly,wl); fz=__shfl(lz,wl);
  }
}

// ---------------- gather sampled points ----------------
__global__ __launch_bounds__(256) void k_gather(const float4* __restrict__ pts4, const int* __restrict__ sidx,
    float4* __restrict__ spts4) {
  int q = blockIdx.x*256 + threadIdx.x;
  spts4[q] = pts4[sidx[q]];
}

// ---------------- TransitionDown pass 1 ----------------
__global__ __launch_bounds__(256) void k_d1(const float* __restrict__ skip, const int* __restrict__ idx2,
    const float* __restrict__ Wd1, float* __restrict__ t1, float* __restrict__ st) {
  __shared__ float wl[4096];
  __shared__ float red[2][4][64];
  for (int t=threadIdx.x;t<4096;t+=256) wl[t]=Wd1[t];
  int w=threadIdx.x>>6, c=threadIdx.x&63;
  __syncthreads();
  float s=0.f,sq=0.f;
  int row0 = blockIdx.x*64 + w*16;
  for (int t=0;t<16;t++){
    int r=row0+t; int src=idx2[r];
    float kf = skip[src*CO+c];
    float o = waveGemm64(kf, wl, c);
    t1[r*CO+c]=o; s+=o; sq=fmaf(o,o,sq);
  }
  red[0][w][c]=s; red[1][w][c]=sq;
  __syncthreads();
  if (w==0){
    float a=red[0][0][c]+red[0][1][c]+red[0][2][c]+red[0][3][c];
    float b=red[1][0][c]+red[1][1][c]+red[1][2][c]+red[1][3][c];
    atomicAdd(&st[c],a); atomicAdd(&st[64+c],b);
  }
}

// ---------------- TransitionDown pass 2 ----------------
__global__ __launch_bounds__(256) void k_d2(const float* __restrict__ t1in, const float* __restrict__ stin,
    const float* __restrict__ gd1, const float* __restrict__ bd1, const float* __restrict__ Wd2,
    float* __restrict__ t2, float* __restrict__ st) {
  __shared__ float wl[4096];
  __shared__ float red[2][4][64];
  for (int t=threadIdx.x;t<4096;t+=256) wl[t]=Wd2[t];
  int w=threadIdx.x>>6, c=threadIdx.x&63;
  const float invn = 1.f/(float)(SP*KK);
  float m=stin[c]*invn; float va=stin[64+c]*invn-m*m; float rs=1.f/sqrtf(va+1e-5f);
  float g=gd1[c], bb=bd1[c];
  __syncthreads();
  float s=0.f,sq=0.f;
  int row0 = blockIdx.x*64 + w*16;
  for (int t=0;t<16;t++){
    int r=row0+t;
    float h = (t1in[r*CO+c]-m)*rs; h = fmaxf(fmaf(h,g,bb),0.f);
    float o = waveGemm64(h, wl, c);
    t2[r*CO+c]=o; s+=o; sq=fmaf(o,o,sq);
  }
  red[0][w][c]=s; red[1][w][c]=sq;
  __syncthreads();
  if (w==0){
    float a=red[0][0][c]+red[0][1][c]+red[0][2][c]+red[0][3][c];
    float b=red[1][0][c]+red[1][1][c]+red[1][2][c]+red[1][3][c];
    atomicAdd(&st[c],a); atomicAdd(&st[64+c],b);
  }
}

// ---------------- down_f = max_k relu(bn(t2)); df = down_f @ Wdn + bdn ----------------
__global__ __launch_bounds__(256) void k_downf(const float* __restrict__ t2, const float* __restrict__ stin,
    const float* __restrict__ gd2, const float* __restrict__ bd2, const float* __restrict__ Wdn,
    const float* __restrict__ bdn, float* __restrict__ df) {
  __shared__ float wl[4096];
  for (int t=threadIdx.x;t<4096;t+=256) wl[t]=Wdn[t];
  int w=threadIdx.x>>6, c=threadIdx.x&63;
  int srow = blockIdx.x*4 + w;
  const float invn = 1.f/(float)(SP*KK);
  float m=stin[c]*invn; float va=stin[64+c]*invn-m*m; float rs=1.f/sqrtf(va+1e-5f);
  float g=gd2[c], bb=bd2[c];
  __syncthreads();
  float mx=-3.4e38f;
  for (int k=0;k<16;k++){
    float h=(t2[(srow*16+k)*CO+c]-m)*rs; h=fmaxf(fmaf(h,g,bb),0.f);
    mx=fmaxf(mx,h);
  }
  float o = waveGemm64(mx, wl, c) + bdn[c];
  df[srow*CO+c]=o;
}

// ---------------- KNN k=3 with distances ----------------
__global__ __launch_bounds__(256,4) void k_knn3(const float4* __restrict__ qp, const float4* __restrict__ cp,
    int* __restrict__ idx3, float* __restrict__ d3) {
  __shared__ float4 tile[2048];
  int q = blockIdx.x*256 + threadIdx.x;
  float4 Q = qp[q];
  float v0=3.4e38f,v1=3.4e38f,v2=3.4e38f;
  int i0=0x7fffffff,i1=0x7fffffff,i2=0x7fffffff;
  for (int base=0;base<SP;base+=2048){
    __syncthreads();
    for (int tt=threadIdx.x;tt<2048;tt+=256) tile[tt]=cp[base+tt];
    __syncthreads();
    for (int j=0;j<2048;j++){
      float4 cpt = tile[j];
      float dot = Q.x*cpt.x + Q.y*cpt.y + Q.z*cpt.z;
      float d = fmaf(-2.f, dot, Q.w) + cpt.w;
      if (d < v2){
        int gj = base+j;
        bool s2 = d < v1;             // shift v1 -> v2 ?
        bool s1 = d < v0;             // shift v0 -> v1 ?
        v2 = s2 ? v1 : d;  i2 = s2 ? i1 : gj;
        v1 = s2 ? (s1 ? v0 : d) : v1; i1 = s2 ? (s1 ? i0 : gj) : i1;
        v0 = s1 ? d : v0;  i0 = s1 ? gj : i0;
      }
    }
  }
  idx3[q*3]=i0; idx3[q*3+1]=i1; idx3[q*3+2]=i2;
  d3[q*3]=v0; d3[q*3+1]=v1; d3[q*3+2]=v2;
}

// ---------------- final: interp + skip @ Wup + bup ----------------
__global__ __launch_bounds__(256) void k_out(const float* __restrict__ df, const int* __restrict__ idx3,
    const float* __restrict__ d3, const float* __restrict__ skip, const float* __restrict__ Wup,
    const float* __restrict__ bup, float* __restrict__ out) {
  __shared__ float wl[4096];
  for (int t=threadIdx.x;t<4096;t+=256) wl[t]=Wup[t];
  int w=threadIdx.x>>6, c=threadIdx.x&63;
  int i = blockIdx.x*4 + w;
  __syncthreads();
  int j0=idx3[i*3], j1=idx3[i*3+1], j2=idx3[i*3+2];
  float e0=d3[i*3], e1=d3[i*3+1], e2=d3[i*3+2];
  float r0=1.f/(e0+1e-8f), r1=1.f/(e1+1e-8f), r2=1.f/(e2+1e-8f);
  float sm=(r0+r1)+r2;
  float w0=r0/sm, w1=r1/sm, w2=r2/sm;
  float interp = (w0*df[j0*CO+c] + w1*df[j1*CO+c]) + w2*df[j2*CO+c];
  float sk = skip[i*CO+c];
  float up = waveGemm64(sk, wl, c);
  out[i*CO+c] = (interp + up) + bup[c];
}

// ---------------- launch ----------------
extern "C" void kernel_launch(void* const* d_in, const int* in_sizes, int n_in,
                              void* d_out, int out_size, void* d_ws, size_t ws_size,
                              hipStream_t stream) {
  (void)in_sizes; (void)n_in; (void)out_size; (void)ws_size;
  const float* points   = (const float*)d_in[0];
  const float* features = (const float*)d_in[1];
  const float* Wq  = (const float*)d_in[2];
  const float* Wk  = (const float*)d_in[3];
  const float* Wv  = (const float*)d_in[4];
  const float* ga1 = (const float*)d_in[5];
  const float* ba1 = (const float*)d_in[6];
  const float* Wa1 = (const float*)d_in[7];
  const float* ga2 = (const float*)d_in[8];
  const float* ba2 = (const float*)d_in[9];
  const float* Wa2 = (const float*)d_in[10];
  const float* b_a2= (const float*)d_in[11];
  const float* Wp1 = (const float*)d_in[12];
  const float* gp  = (const float*)d_in[13];
  const float* bp  = (const float*)d_in[14];
  const float* Wp2 = (const float*)d_in[15];
  const float* Wd1 = (const float*)d_in[16];
  const float* gd1 = (const float*)d_in[17];
  const float* bd1 = (const float*)d_in[18];
  const float* Wd2 = (const float*)d_in[19];
  const float* gd2 = (const float*)d_in[20];
  const float* bd2 = (const float*)d_in[21];
  const float* Wup = (const float*)d_in[22];
  const float* bup = (const float*)d_in[23];
  const float* Wdn = (const float*)d_in[24];
  const float* bdn = (const float*)d_in[25];
  float* out = (float*)d_out;

  char* wp = (char*)d_ws;
  auto carve = [&](size_t bytes)->char* { char* p = wp; wp += (bytes + 255) & ~(size_t)255; return p; };
  float4* pts4  = (float4*)carve((size_t)NP*16);
  float*  fq    = (float*) carve((size_t)NP*CO*4);
  float*  fk    = (float*) carve((size_t)NP*CO*4);
  float*  fv    = (float*) carve((size_t)NP*CO*4);
  int*    kidx  = (int*)   carve((size_t)NP*KK*4);
  float*  y     = (float*) carve((size_t)NP*KK*3*4);
  float*  yn    = (float*) carve((size_t)NP*KK*3*4);
  float*  skip  = (float*) carve((size_t)NP*CO*4);
  int*    sidx  = (int*)   carve((size_t)SP*4);
  float4* spts4 = (float4*)carve((size_t)SP*16);
  int*    idx2  = (int*)   carve((size_t)SP*KK*4);
  float*  t1    = (float*) carve((size_t)SP*KK*CO*4);   // 16MB; split bufs alias head
  float*  t2    = (float*) carve((size_t)SP*KK*CO*4);   // 16MB
  float*  df    = (float*) carve((size_t)SP*CO*4);
  int*    idx3  = (int*)   carve((size_t)NP*3*4);
  float*  d3    = (float*) carve((size_t)NP*3*4);
  float4* coordsT = (float4*)carve((size_t)NP*16);      // transposed Morton points for FPS
  float*  bbox  = (float*) carve(256);
  int*    cellStart = (int*)carve((size_t)NCELLS*4);
  float*  stats = (float*) carve(4096);
  int*    hist  = (int*)   carve((size_t)NCELLS*4);
  int*    cursor= (int*)   carve((size_t)NCELLS*4);
  float* stRel = stats;        // 6 floats
  float* stX   = stats + 8;    // 128
  float* stX1  = stats + 136;  // 128
  float* stD1  = stats + 264;  // 128
  float* stD2  = stats + 392;  // 128
  // KNN split buffers alias t1/t2 (consumed by merges before k_d1/k_d2 write them)
  float* psvNP = t1;                         // 16384*4*16*4B = 4MB
  int*   psiNP = (int*)(t1 + (size_t)NP*4*KK);
  float* psvSP = t2;                         // 4096*8*16*4B = 2MB
  int*   psiSP = (int*)(t2 + (size_t)SP*8*KK);

  hipMemsetAsync(stats, 0, 4096 + NCELLS*4*2, stream);

  k_pts4   <<<NP/256, 256, 0, stream>>>(points, pts4);
  // binning for FPS
  k_bbox     <<<1, 1024, 0, stream>>>(pts4, bbox);
  k_cellhist <<<NP/256, 256, 0, stream>>>(pts4, bbox, hist);
  k_scan     <<<1, 1024, 0, stream>>>(hist, cellStart);
  k_scatter  <<<NP/256, 256, 0, stream>>>(pts4, bbox, cellStart, cursor, coordsT);
  // transformer layer
  k_qkv    <<<NP/4,   256, 0, stream>>>(features, Wq, Wk, Wv, fq, fk, fv);
  k_knn16p <<<dim3(NP/256,4), 256, 0, stream>>>(pts4, pts4, NP/4, psvNP, psiNP);
  k_merge<4><<<NP/256, 256, 0, stream>>>(psvNP, psiNP, kidx);
  k_rel    <<<NP*KK/256, 256, 0, stream>>>(pts4, kidx, Wp1, y, stRel);
  k_yn     <<<NP*KK/256, 256, 0, stream>>>(y, stRel, gp, bp, yn);
  k_xstats <<<NP*KK/256, 256, 0, stream>>>(fq, fk, kidx, yn, Wp2, stX);
  k_x1stats<<<NP*KK/128, 256, 0, stream>>>(fq, fk, kidx, yn, Wp2, Wa1, ga1, ba1, stX, stX1);
  k_attn   <<<NP/4,   256, 0, stream>>>(fq, fk, fv, kidx, yn, Wp2, Wa1, Wa2, ga1, ba1, ga2, ba2, b_a2, stX, stX1, skip);
  // down / up
  k_fps    <<<1,       64, 0, stream>>>(pts4, coordsT, sidx);
  k_gather <<<SP/256, 256, 0, stream>>>(pts4, sidx, spts4);
  k_knn16p <<<dim3(SP/256,8), 256, 0, stream>>>(spts4, pts4, NP/8, psvSP, psiSP);
  k_merge<8><<<SP/256, 256, 0, stream>>>(psvSP, psiSP, idx2);
  k_d1     <<<SP*KK/64, 256, 0, stream>>>(skip, idx2, Wd1, t1, stD1);
  k_d2     <<<SP*KK/64, 256, 0, stream>>>(t1, stD1, gd1, bd1, Wd2, t2, stD2);
  k_downf  <<<SP/4,   256, 0, stream>>>(t2, stD2, gd2, bd2, Wdn, bdn, df);
  k_knn3   <<<NP/256, 256, 0, stream>>>(pts4, spts4, idx3, d3);
  k_out    <<<NP/4,   256, 0, stream>>>(df, idx3, d3, skip, Wup, bup, out);
}

// Round 6
// 12715.163 us; speedup vs baseline: 9.7853x; 9.7853x over previous
//
#include <hip/hip_runtime.h>
#include <math.h>

#define NP 16384
#define SP 4096
#define CINCH 32
#define CO 64
#define KK 16
#define NSPIN 128   // spinner blocks to hold clocks up during serial FPS

// ---------------- helpers ----------------
__device__ __forceinline__ float waveGemm64(float xv, const float* __restrict__ wl, int c) {
  float a0=0.f,a1=0.f,a2=0.f,a3=0.f;
  #pragma unroll
  for (int k=0;k<64;k+=4){
    a0 = fmaf(__shfl(xv,k  ), wl[(k  )*CO+c], a0);
    a1 = fmaf(__shfl(xv,k+1), wl[(k+1)*CO+c], a1);
    a2 = fmaf(__shfl(xv,k+2), wl[(k+2)*CO+c], a2);
    a3 = fmaf(__shfl(xv,k+3), wl[(k+3)*CO+c], a3);
  }
  return (a0+a1)+(a2+a3);
}

// ---------------- pts4: pack xyz + |p|^2 ----------------
__global__ __launch_bounds__(256) void k_pts4(const float* __restrict__ pts, float4* __restrict__ pts4) {
  int i = blockIdx.x*256 + threadIdx.x;
  float x = pts[3*i], y = pts[3*i+1], z = pts[3*i+2];
  pts4[i] = make_float4(x,y,z, x*x + y*y + z*z);
}

// ---------------- QKV projections ----------------
__global__ __launch_bounds__(256) void k_qkv(const float* __restrict__ feat,
    const float* __restrict__ Wq, const float* __restrict__ Wk, const float* __restrict__ Wv,
    float* __restrict__ fq, float* __restrict__ fk, float* __restrict__ fv) {
  int r = threadIdx.x >> 6, c = threadIdx.x & 63;
  int row = blockIdx.x*4 + r;
  const float* f = feat + row*CINCH;
  float aq=0.f, ak=0.f, av=0.f;
  #pragma unroll
  for (int k=0;k<CINCH;k++){
    float fe = f[k];
    aq = fmaf(fe, Wq[k*CO+c], aq);
    ak = fmaf(fe, Wk[k*CO+c], ak);
    av = fmaf(fe, Wv[k*CO+c], av);
  }
  fq[row*CO+c]=aq; fk[row*CO+c]=ak; fv[row*CO+c]=av;
}

// ---------------- KNN16 partial: per-part register top-16 (sorted-shift) ----------------
#define KTS 2048
__global__ __launch_bounds__(256,4) void k_knn16p(const float4* __restrict__ qp,
    const float4* __restrict__ cp, int clen,
    float* __restrict__ psv, int* __restrict__ psi) {
  __shared__ float4 tile[KTS];
  int q = blockIdx.x*256 + threadIdx.x;
  int part = blockIdx.y;
  int nspl = gridDim.y;
  int c0 = part*clen;
  float4 tq = qp[q];
  float qx=tq.x, qy=tq.y, qz=tq.z;
  float v[KK]; int id[KK];
  #pragma unroll
  for (int k=0;k<KK;k++){ v[k]=3.4e38f; id[k]=0x7fffffff; }
  for (int base=c0; base<c0+clen; base+=KTS){
    __syncthreads();
    for (int tt=threadIdx.x;tt<KTS;tt+=256) tile[tt]=cp[base+tt];
    __syncthreads();
    for (int j=0;j<KTS;j++){
      float4 cpt=tile[j];
      float dot = qx*cpt.x + qy*cpt.y + qz*cpt.z;
      float s = fmaf(-2.f,dot,cpt.w);
      if (s < v[KK-1]) {             // strict: equal value stays out (earlier index wins)
        int gj = base+j;
        #pragma unroll
        for (int k=KK-1;k>=1;--k){
          bool sh = s < v[k-1];
          bool pl = s < v[k];        // old v[k]
          float nv = sh ? v[k-1] : (pl ? s  : v[k]);
          int   ni = sh ? id[k-1] : (pl ? gj : id[k]);
          v[k]=nv; id[k]=ni;
        }
        if (s < v[0]){ v[0]=s; id[0]=gj; }
      }
    }
  }
  size_t o = ((size_t)q*nspl + part)*KK;
  #pragma unroll
  for (int k=0;k<KK;k++){ psv[o+k]=v[k]; psi[o+k]=id[k]; }
}

// ---------------- merge NS sorted 16-lists -> top 16 (lexicographic (v,idx)) ----------------
template<int NS>
__global__ __launch_bounds__(256,4) void k_merge(const float* __restrict__ psv,
    const int* __restrict__ psi, int* __restrict__ oidx) {
  int q = blockIdx.x*256 + threadIdx.x;
  const float* pv = psv + (size_t)q*NS*KK;
  const int*   pi = psi + (size_t)q*NS*KK;
  int pos[NS]; float hv[NS]; int hi[NS];
  #pragma unroll
  for (int p=0;p<NS;p++){ pos[p]=0; hv[p]=pv[p*KK]; hi[p]=pi[p*KK]; }
  #pragma unroll
  for (int k=0;k<KK;k++){
    int best=0; float bv=hv[0]; int bi=hi[0];
    #pragma unroll
    for (int p=1;p<NS;p++){
      bool g=(hv[p]<bv)||((hv[p]==bv)&&(hi[p]<bi));
      if (g){ bv=hv[p]; bi=hi[p]; best=p; }
    }
    oidx[q*KK+k]=bi;
    #pragma unroll
    for (int p=0;p<NS;p++) if (best==p){
      pos[p]++;
      bool ok = pos[p]<KK;
      hv[p] = ok ? pv[p*KK+pos[p]] : 3.4e38f;
      hi[p] = ok ? pi[p*KK+pos[p]] : 0x7fffffff;
    }
  }
}

// ---------------- rel = p_i - p_knn ; y = rel @ Wp1 ; stats ----------------
__global__ __launch_bounds__(256) void k_rel(const float4* __restrict__ pts4, const int* __restrict__ kidx,
    const float* __restrict__ Wp1, float* __restrict__ y, float* __restrict__ st) {
  int r = blockIdx.x*256 + threadIdx.x;
  int i = r>>4;
  int j = kidx[r];
  float4 pi=pts4[i], pj=pts4[j];
  float rx=pi.x-pj.x, ry=pi.y-pj.y, rz=pi.z-pj.z;
  float s[3], sq[3];
  #pragma unroll
  for (int c=0;c<3;c++){
    float yc = rx*Wp1[c] + ry*Wp1[3+c] + rz*Wp1[6+c];
    y[r*3+c]=yc; s[c]=yc; sq[c]=yc*yc;
  }
  #pragma unroll
  for (int c=0;c<3;c++){
    float a=s[c], b=sq[c];
    #pragma unroll
    for (int o=32;o;o>>=1){ a+=__shfl_down(a,o); b+=__shfl_down(b,o); }
    if ((threadIdx.x&63)==0){ atomicAdd(&st[c],a); atomicAdd(&st[3+c],b); }
  }
}

// ---------------- yn = relu(bn(y)) ----------------
__global__ __launch_bounds__(256) void k_yn(const float* __restrict__ y, const float* __restrict__ st,
    const float* __restrict__ gp, const float* __restrict__ bp, float* __restrict__ yn) {
  int r = blockIdx.x*256 + threadIdx.x;
  const float invn = 1.f/(float)(NP*KK);
  #pragma unroll
  for (int c=0;c<3;c++){
    float m = st[c]*invn;
    float var = st[3+c]*invn - m*m;
    float rs = 1.f/sqrtf(var+1e-5f);
    float t = (y[r*3+c]-m)*rs;
    t = fmaf(t, gp[c], bp[c]);
    yn[r*3+c] = fmaxf(t,0.f);
  }
}

// ---------------- stats of x = fq - fk[knn] + rpe ----------------
__global__ __launch_bounds__(256) void k_xstats(const float* __restrict__ fq, const float* __restrict__ fk,
    const int* __restrict__ kidx, const float* __restrict__ yn, const float* __restrict__ Wp2,
    float* __restrict__ st) {
  __shared__ float red[2][4][64];
  int w=threadIdx.x>>6, c=threadIdx.x&63;
  float w0=Wp2[c], w1=Wp2[64+c], w2=Wp2[128+c];
  float s=0.f,sq=0.f;
  int row0 = blockIdx.x*256 + w*64;
  for (int t=0;t<64;t++){
    int r=row0+t; int p=r>>4; int j=kidx[r];
    float y0=yn[r*3], y1=yn[r*3+1], y2=yn[r*3+2];
    float x = fq[p*CO+c]-fk[j*CO+c]+(y0*w0+y1*w1+y2*w2);
    s+=x; sq=fmaf(x,x,sq);
  }
  red[0][w][c]=s; red[1][w][c]=sq;
  __syncthreads();
  if (w==0){
    float a=red[0][0][c]+red[0][1][c]+red[0][2][c]+red[0][3][c];
    float b=red[1][0][c]+red[1][1][c]+red[1][2][c]+red[1][3][c];
    atomicAdd(&st[c],a); atomicAdd(&st[64+c],b);
  }
}

// ---------------- stats of x1 = relu(bn1(x)) @ Wa1 ----------------
__global__ __launch_bounds__(256) void k_x1stats(const float* __restrict__ fq,const float* __restrict__ fk,
    const int* __restrict__ kidx, const float* __restrict__ yn, const float* __restrict__ Wp2,
    const float* __restrict__ Wa1, const float* __restrict__ ga1, const float* __restrict__ ba1,
    const float* __restrict__ stx, float* __restrict__ st1) {
  __shared__ float wa1[4096];
  __shared__ float red[2][4][64];
  for (int t=threadIdx.x;t<4096;t+=256) wa1[t]=Wa1[t];
  int w=threadIdx.x>>6, c=threadIdx.x&63;
  const float invn=1.f/(float)(NP*KK);
  float m1=stx[c]*invn; float vv=stx[64+c]*invn-m1*m1; float rs1=1.f/sqrtf(vv+1e-5f);
  float g1=ga1[c], bb1=ba1[c];
  float w0=Wp2[c],w1=Wp2[64+c],w2=Wp2[128+c];
  __syncthreads();
  float s=0.f,sq=0.f;
  int row0 = blockIdx.x*128 + w*32;
  for (int t=0;t<32;t++){
    int r=row0+t; int p=r>>4; int j=kidx[r];
    float y0=yn[r*3],y1=yn[r*3+1],y2=yn[r*3+2];
    float x = fq[p*CO+c]-fk[j*CO+c]+(y0*w0+y1*w1+y2*w2);
    float tt=(x-m1)*rs1; tt=fmaxf(fmaf(tt,g1,bb1),0.f);
    float x1 = waveGemm64(tt, wa1, c);
    s += x1; sq = fmaf(x1,x1,sq);
  }
  red[0][w][c]=s; red[1][w][c]=sq;
  __syncthreads();
  if (w==0){
    float a=red[0][0][c]+red[0][1][c]+red[0][2][c]+red[0][3][c];
    float b=red[1][0][c]+red[1][1][c]+red[1][2][c]+red[1][3][c];
    atomicAdd(&st1[c],a); atomicAdd(&st1[64+c],b);
  }
}

// ---------------- attention: x2, softmax over K, skip ----------------
__global__ __launch_bounds__(256) void k_attn(const float* __restrict__ fq,const float* __restrict__ fk,
    const float* __restrict__ fv,const int* __restrict__ kidx,const float* __restrict__ yn,
    const float* __restrict__ Wp2,const float* __restrict__ Wa1,const float* __restrict__ Wa2,
    const float* __restrict__ ga1,const float* __restrict__ ba1,const float* __restrict__ ga2,
    const float* __restrict__ ba2,const float* __restrict__ b_a2,
    const float* __restrict__ stx,const float* __restrict__ st1, float* __restrict__ skip) {
  __shared__ float wa1[4096], wa2[4096];
  __shared__ float sc[4][16][64];
  for (int t=threadIdx.x;t<4096;t+=256){ wa1[t]=Wa1[t]; wa2[t]=Wa2[t]; }
  int w=threadIdx.x>>6, c=threadIdx.x&63;
  int p = blockIdx.x*4 + w;
  const float invn = 1.f/(float)(NP*KK);
  float m1=stx[c]*invn; float va=stx[64+c]*invn-m1*m1; float rs1=1.f/sqrtf(va+1e-5f);
  float m2=st1[c]*invn; float vb=st1[64+c]*invn-m2*m2; float rs2=1.f/sqrtf(vb+1e-5f);
  float g1=ga1[c], bb1=ba1[c], g2=ga2[c], bb2=ba2[c], bc=b_a2[c];
  float w0=Wp2[c], w1=Wp2[64+c], w2=Wp2[128+c];
  float fqv = fq[p*CO+c];
  __syncthreads();
  for (int k=0;k<16;k++){
    int r=p*16+k; int j=kidx[r];
    float y0=yn[r*3],y1=yn[r*3+1],y2=yn[r*3+2];
    float x = fqv - fk[j*CO+c] + (y0*w0+y1*w1+y2*w2);
    float t1 = (x-m1)*rs1; t1 = fmaxf(fmaf(t1,g1,bb1),0.f);
    float x1 = waveGemm64(t1, wa1, c);
    float t2 = (x1-m2)*rs2; t2 = fmaxf(fmaf(t2,g2,bb2),0.f);
    float x2 = waveGemm64(t2, wa2, c) + bc;
    sc[w][k][c] = x2;
  }
  float mx = sc[w][0][c];
  #pragma unroll
  for (int k=1;k<16;k++) mx = fmaxf(mx, sc[w][k][c]);
  float sum=0.f;
  for (int k=0;k<16;k++){ float e=expf(sc[w][k][c]-mx); sc[w][k][c]=e; sum+=e; }
  float acc=0.f;
  for (int k=0;k<16;k++){
    int r=p*16+k; int j=kidx[r];
    float y0=yn[r*3],y1=yn[r*3+1],y2=yn[r*3+2];
    float rpe = y0*w0+y1*w1+y2*w2;
    acc = fmaf(sc[w][k][c], fv[j*CO+c]+rpe, acc);
  }
  skip[p*CO+c] = acc/sum;
}

// ---------------- FPS v6: round-1 structure + clock-keeper spinner blocks ----------------
// Block 0: 16 waves x 16 pts/thread, full update, butterfly + 2-barrier LDS
// reduce (the empirically fastest 2.15us/step structure). Blocks 1..NSPIN:
// dependent-FMA bursts to keep the SMU from parking the clock (the DVFS
// hypothesis for why low-activity variants ran 3-70x slower). Spinners write
// nothing; they exit when block 0 sets *done (zeroed by memset each launch,
// polled via device-scope atomic; fanned out via LDS flag). Grid = 129 blocks
// << 256 CUs -> all co-resident, no deadlock.
__global__ __launch_bounds__(1024,4) void k_fps(const float4* __restrict__ pts4,
    int* __restrict__ sidx, int* __restrict__ done) {
  #pragma clang fp contract(off)
  if (blockIdx.x != 0){
    __shared__ int sdone;
    if (threadIdx.x==0) sdone=0;
    __syncthreads();
    float a = 1.f + (float)threadIdx.x*1e-7f;
    const float b = 1.0000001f;
    while (__hip_atomic_load(&sdone, __ATOMIC_RELAXED, __HIP_MEMORY_SCOPE_WORKGROUP)==0){
      #pragma unroll 32
      for (int i=0;i<4096;i++) a = fmaf(a,b,1e-12f);
      asm volatile("" :: "v"(a));
      if (threadIdx.x==0 && atomicAdd(done,0)!=0)
        __hip_atomic_store(&sdone, 1, __ATOMIC_RELAXED, __HIP_MEMORY_SCOPE_WORKGROUP);
    }
    return;
  }
  __shared__ float rbv[16];
  __shared__ int rbi[16];
  int t = threadIdx.x;
  float px[16],py[16],pz[16],dm[16];
  #pragma unroll
  for (int m=0;m<16;m++){
    float4 p = pts4[t*16+m];
    px[m]=p.x; py[m]=p.y; pz[m]=p.z; dm[m]=1e10f;
  }
  int far = 0;
  float4 f0 = pts4[0];
  float fx=f0.x, fy=f0.y, fz=f0.z;
  for (int s=0;s<SP;s++){
    if (t==0) sidx[s]=far;
    float bv=-1.f; int bi=0;
    #pragma unroll
    for (int m=0;m<16;m++){
      float dx=px[m]-fx, dy=py[m]-fy, dz=pz[m]-fz;
      float q0=dx*dx, q1=dy*dy, q2=dz*dz;
      float d=(q0+q1)+q2;                 // matches ((d0+d1)+d2), no FMA
      float nd=fminf(dm[m],d);
      dm[m]=nd;
      bool g = nd>bv;                     // strict: ties keep lower index
      bv = g?nd:bv;
      bi = g?(t*16+m):bi;
    }
    #pragma unroll
    for (int o=1;o<64;o<<=1){
      float ov=__shfl_xor(bv,o); int oi=__shfl_xor(bi,o);
      bool g = (ov>bv)||((ov==bv)&&(oi<bi));
      bv=g?ov:bv; bi=g?oi:bi;
    }
    __syncthreads();
    if ((t&63)==0){ rbv[t>>6]=bv; rbi[t>>6]=bi; }
    __syncthreads();
    float cv=rbv[t&15]; int ci=rbi[t&15];
    #pragma unroll
    for (int o=1;o<16;o<<=1){
      float ov=__shfl_xor(cv,o); int oi=__shfl_xor(ci,o);
      bool g=(ov>cv)||((ov==cv)&&(oi<ci));
      cv=g?ov:cv; ci=g?oi:ci;
    }
    far = ci;
    float4 fp = pts4[far];
    fx=fp.x; fy=fp.y; fz=fp.z;
  }
  if (t==0) atomicAdd(done,1);   // release spinners
}

// ---------------- gather sampled points ----------------
__global__ __launch_bounds__(256) void k_gather(const float4* __restrict__ pts4, const int* __restrict__ sidx,
    float4* __restrict__ spts4) {
  int q = blockIdx.x*256 + threadIdx.x;
  spts4[q] = pts4[sidx[q]];
}

// ---------------- TransitionDown pass 1 ----------------
__global__ __launch_bounds__(256) void k_d1(const float* __restrict__ skip, const int* __restrict__ idx2,
    const float* __restrict__ Wd1, float* __restrict__ t1, float* __restrict__ st) {
  __shared__ float wl[4096];
  __shared__ float red[2][4][64];
  for (int t=threadIdx.x;t<4096;t+=256) wl[t]=Wd1[t];
  int w=threadIdx.x>>6, c=threadIdx.x&63;
  __syncthreads();
  float s=0.f,sq=0.f;
  int row0 = blockIdx.x*64 + w*16;
  for (int t=0;t<16;t++){
    int r=row0+t; int src=idx2[r];
    float kf = skip[src*CO+c];
    float o = waveGemm64(kf, wl, c);
    t1[r*CO+c]=o; s+=o; sq=fmaf(o,o,sq);
  }
  red[0][w][c]=s; red[1][w][c]=sq;
  __syncthreads();
  if (w==0){
    float a=red[0][0][c]+red[0][1][c]+red[0][2][c]+red[0][3][c];
    float b=red[1][0][c]+red[1][1][c]+red[1][2][c]+red[1][3][c];
    atomicAdd(&st[c],a); atomicAdd(&st[64+c],b);
  }
}

// ---------------- TransitionDown pass 2 ----------------
__global__ __launch_bounds__(256) void k_d2(const float* __restrict__ t1in, const float* __restrict__ stin,
    const float* __restrict__ gd1, const float* __restrict__ bd1, const float* __restrict__ Wd2,
    float* __restrict__ t2, float* __restrict__ st) {
  __shared__ float wl[4096];
  __shared__ float red[2][4][64];
  for (int t=threadIdx.x;t<4096;t+=256) wl[t]=Wd2[t];
  int w=threadIdx.x>>6, c=threadIdx.x&63;
  const float invn = 1.f/(float)(SP*KK);
  float m=stin[c]*invn; float va=stin[64+c]*invn-m*m; float rs=1.f/sqrtf(va+1e-5f);
  float g=gd1[c], bb=bd1[c];
  __syncthreads();
  float s=0.f,sq=0.f;
  int row0 = blockIdx.x*64 + w*16;
  for (int t=0;t<16;t++){
    int r=row0+t;
    float h = (t1in[r*CO+c]-m)*rs; h = fmaxf(fmaf(h,g,bb),0.f);
    float o = waveGemm64(h, wl, c);
    t2[r*CO+c]=o; s+=o; sq=fmaf(o,o,sq);
  }
  red[0][w][c]=s; red[1][w][c]=sq;
  __syncthreads();
  if (w==0){
    float a=red[0][0][c]+red[0][1][c]+red[0][2][c]+red[0][3][c];
    float b=red[1][0][c]+red[1][1][c]+red[1][2][c]+red[1][3][c];
    atomicAdd(&st[c],a); atomicAdd(&st[64+c],b);
  }
}

// ---------------- down_f = max_k relu(bn(t2)); df = down_f @ Wdn + bdn ----------------
__global__ __launch_bounds__(256) void k_downf(const float* __restrict__ t2, const float* __restrict__ stin,
    const float* __restrict__ gd2, const float* __restrict__ bd2, const float* __restrict__ Wdn,
    const float* __restrict__ bdn, float* __restrict__ df) {
  __shared__ float wl[4096];
  for (int t=threadIdx.x;t<4096;t+=256) wl[t]=Wdn[t];
  int w=threadIdx.x>>6, c=threadIdx.x&63;
  int srow = blockIdx.x*4 + w;
  const float invn = 1.f/(float)(SP*KK);
  float m=stin[c]*invn; float va=stin[64+c]*invn-m*m; float rs=1.f/sqrtf(va+1e-5f);
  float g=gd2[c], bb=bd2[c];
  __syncthreads();
  float mx=-3.4e38f;
  for (int k=0;k<16;k++){
    float h=(t2[(srow*16+k)*CO+c]-m)*rs; h=fmaxf(fmaf(h,g,bb),0.f);
    mx=fmaxf(mx,h);
  }
  float o = waveGemm64(mx, wl, c) + bdn[c];
  df[srow*CO+c]=o;
}

// ---------------- KNN k=3 with distances ----------------
__global__ __launch_bounds__(256,4) void k_knn3(const float4* __restrict__ qp, const float4* __restrict__ cp,
    int* __restrict__ idx3, float* __restrict__ d3) {
  __shared__ float4 tile[2048];
  int q = blockIdx.x*256 + threadIdx.x;
  float4 Q = qp[q];
  float v0=3.4e38f,v1=3.4e38f,v2=3.4e38f;
  int i0=0x7fffffff,i1=0x7fffffff,i2=0x7fffffff;
  for (int base=0;base<SP;base+=2048){
    __syncthreads();
    for (int tt=threadIdx.x;tt<2048;tt+=256) tile[tt]=cp[base+tt];
    __syncthreads();
    for (int j=0;j<2048;j++){
      float4 cpt = tile[j];
      float dot = Q.x*cpt.x + Q.y*cpt.y + Q.z*cpt.z;
      float d = fmaf(-2.f, dot, Q.w) + cpt.w;
      if (d < v2){
        int gj = base+j;
        bool s2 = d < v1;             // shift v1 -> v2 ?
        bool s1 = d < v0;             // shift v0 -> v1 ?
        v2 = s2 ? v1 : d;  i2 = s2 ? i1 : gj;
        v1 = s2 ? (s1 ? v0 : d) : v1; i1 = s2 ? (s1 ? i0 : gj) : i1;
        v0 = s1 ? d : v0;  i0 = s1 ? gj : i0;
      }
    }
  }
  idx3[q*3]=i0; idx3[q*3+1]=i1; idx3[q*3+2]=i2;
  d3[q*3]=v0; d3[q*3+1]=v1; d3[q*3+2]=v2;
}

// ---------------- final: interp + skip @ Wup + bup ----------------
__global__ __launch_bounds__(256) void k_out(const float* __restrict__ df, const int* __restrict__ idx3,
    const float* __restrict__ d3, const float* __restrict__ skip, const float* __restrict__ Wup,
    const float* __restrict__ bup, float* __restrict__ out) {
  __shared__ float wl[4096];
  for (int t=threadIdx.x;t<4096;t+=256) wl[t]=Wup[t];
  int w=threadIdx.x>>6, c=threadIdx.x&63;
  int i = blockIdx.x*4 + w;
  __syncthreads();
  int j0=idx3[i*3], j1=idx3[i*3+1], j2=idx3[i*3+2];
  float e0=d3[i*3], e1=d3[i*3+1], e2=d3[i*3+2];
  float r0=1.f/(e0+1e-8f), r1=1.f/(e1+1e-8f), r2=1.f/(e2+1e-8f);
  float sm=(r0+r1)+r2;
  float w0=r0/sm, w1=r1/sm, w2=r2/sm;
  float interp = (w0*df[j0*CO+c] + w1*df[j1*CO+c]) + w2*df[j2*CO+c];
  float sk = skip[i*CO+c];
  float up = waveGemm64(sk, wl, c);
  out[i*CO+c] = (interp + up) + bup[c];
}

// ---------------- launch ----------------
extern "C" void kernel_launch(void* const* d_in, const int* in_sizes, int n_in,
                              void* d_out, int out_size, void* d_ws, size_t ws_size,
                              hipStream_t stream) {
  (void)in_sizes; (void)n_in; (void)out_size; (void)ws_size;
  const float* points   = (const float*)d_in[0];
  const float* features = (const float*)d_in[1];
  const float* Wq  = (const float*)d_in[2];
  const float* Wk  = (const float*)d_in[3];
  const float* Wv  = (const float*)d_in[4];
  const float* ga1 = (const float*)d_in[5];
  const float* ba1 = (const float*)d_in[6];
  const float* Wa1 = (const float*)d_in[7];
  const float* ga2 = (const float*)d_in[8];
  const float* ba2 = (const float*)d_in[9];
  const float* Wa2 = (const float*)d_in[10];
  const float* b_a2= (const float*)d_in[11];
  const float* Wp1 = (const float*)d_in[12];
  const float* gp  = (const float*)d_in[13];
  const float* bp  = (const float*)d_in[14];
  const float* Wp2 = (const float*)d_in[15];
  const float* Wd1 = (const float*)d_in[16];
  const float* gd1 = (const float*)d_in[17];
  const float* bd1 = (const float*)d_in[18];
  const float* Wd2 = (const float*)d_in[19];
  const float* gd2 = (const float*)d_in[20];
  const float* bd2 = (const float*)d_in[21];
  const float* Wup = (const float*)d_in[22];
  const float* bup = (const float*)d_in[23];
  const float* Wdn = (const float*)d_in[24];
  const float* bdn = (const float*)d_in[25];
  float* out = (float*)d_out;

  char* wp = (char*)d_ws;
  auto carve = [&](size_t bytes)->char* { char* p = wp; wp += (bytes + 255) & ~(size_t)255; return p; };
  float4* pts4  = (float4*)carve((size_t)NP*16);
  float*  fq    = (float*) carve((size_t)NP*CO*4);
  float*  fk    = (float*) carve((size_t)NP*CO*4);
  float*  fv    = (float*) carve((size_t)NP*CO*4);
  int*    kidx  = (int*)   carve((size_t)NP*KK*4);
  float*  y     = (float*) carve((size_t)NP*KK*3*4);
  float*  yn    = (float*) carve((size_t)NP*KK*3*4);
  float*  skip  = (float*) carve((size_t)NP*CO*4);
  int*    sidx  = (int*)   carve((size_t)SP*4);
  float4* spts4 = (float4*)carve((size_t)SP*16);
  int*    idx2  = (int*)   carve((size_t)SP*KK*4);
  float*  t1    = (float*) carve((size_t)SP*KK*CO*4);   // 16MB; split bufs alias head
  float*  t2    = (float*) carve((size_t)SP*KK*CO*4);   // 16MB
  float*  df    = (float*) carve((size_t)SP*CO*4);
  int*    idx3  = (int*)   carve((size_t)NP*3*4);
  float*  d3    = (float*) carve((size_t)NP*3*4);
  float*  stats = (float*) carve(4096);                 // zeroed each launch
  float* stRel = stats;        // 6 floats
  float* stX   = stats + 8;    // 128
  float* stX1  = stats + 136;  // 128
  float* stD1  = stats + 264;  // 128
  float* stD2  = stats + 392;  // 128
  int*   done  = (int*)(stats + 768);  // spinner release flag
  // KNN split buffers alias t1/t2 (consumed by merges before k_d1/k_d2 write them)
  float* psvNP = t1;                         // 16384*4*16*4B = 4MB
  int*   psiNP = (int*)(t1 + (size_t)NP*4*KK);
  float* psvSP = t2;                         // 4096*8*16*4B = 2MB
  int*   psiSP = (int*)(t2 + (size_t)SP*8*KK);

  hipMemsetAsync(stats, 0, 4096, stream);

  k_pts4   <<<NP/256, 256, 0, stream>>>(points, pts4);
  // transformer layer
  k_qkv    <<<NP/4,   256, 0, stream>>>(features, Wq, Wk, Wv, fq, fk, fv);
  k_knn16p <<<dim3(NP/256,4), 256, 0, stream>>>(pts4, pts4, NP/4, psvNP, psiNP);
  k_merge<4><<<NP/256, 256, 0, stream>>>(psvNP, psiNP, kidx);
  k_rel    <<<NP*KK/256, 256, 0, stream>>>(pts4, kidx, Wp1, y, stRel);
  k_yn     <<<NP*KK/256, 256, 0, stream>>>(y, stRel, gp, bp, yn);
  k_xstats <<<NP*KK/256, 256, 0, stream>>>(fq, fk, kidx, yn, Wp2, stX);
  k_x1stats<<<NP*KK/128, 256, 0, stream>>>(fq, fk, kidx, yn, Wp2, Wa1, ga1, ba1, stX, stX1);
  k_attn   <<<NP/4,   256, 0, stream>>>(fq, fk, fv, kidx, yn, Wp2, Wa1, Wa2, ga1, ba1, ga2, ba2, b_a2, stX, stX1, skip);
  // down / up
  k_fps    <<<1+NSPIN, 1024, 0, stream>>>(pts4, sidx, done);
  k_gather <<<SP/256, 256, 0, stream>>>(pts4, sidx, spts4);
  k_knn16p <<<dim3(SP/256,8), 256, 0, stream>>>(spts4, pts4, NP/8, psvSP, psiSP);
  k_merge<8><<<SP/256, 256, 0, stream>>>(psvSP, psiSP, idx2);
  k_d1     <<<SP*KK/64, 256, 0, stream>>>(skip, idx2, Wd1, t1, stD1);
  k_d2     <<<SP*KK/64, 256, 0, stream>>>(t1, stD1, gd1, bd1, Wd2, t2, stD2);
  k_downf  <<<SP/4,   256, 0, stream>>>(t2, stD2, gd2, bd2, Wdn, bdn, df);
  k_knn3   <<<NP/256, 256, 0, stream>>>(pts4, spts4, idx3, d3);
  k_out    <<<NP/4,   256, 0, stream>>>(df, idx3, d3, skip, Wup, bup, out);
}

// Round 7
// 12539.936 us; speedup vs baseline: 9.9220x; 1.0140x over previous
//
#include <hip/hip_runtime.h>
#include <math.h>

#define NP 16384
#define SP 4096
#define CINCH 32
#define CO 64
#define KK 16

// ---------------- helpers ----------------
__device__ __forceinline__ float waveGemm64(float xv, const float* __restrict__ wl, int c) {
  float a0=0.f,a1=0.f,a2=0.f,a3=0.f;
  #pragma unroll
  for (int k=0;k<64;k+=4){
    a0 = fmaf(__shfl(xv,k  ), wl[(k  )*CO+c], a0);
    a1 = fmaf(__shfl(xv,k+1), wl[(k+1)*CO+c], a1);
    a2 = fmaf(__shfl(xv,k+2), wl[(k+2)*CO+c], a2);
    a3 = fmaf(__shfl(xv,k+3), wl[(k+3)*CO+c], a3);
  }
  return (a0+a1)+(a2+a3);
}

// ---------------- pts4: pack xyz + |p|^2 ----------------
__global__ __launch_bounds__(256) void k_pts4(const float* __restrict__ pts, float4* __restrict__ pts4) {
  int i = blockIdx.x*256 + threadIdx.x;
  float x = pts[3*i], y = pts[3*i+1], z = pts[3*i+2];
  pts4[i] = make_float4(x,y,z, x*x + y*y + z*z);
}

// ---------------- QKV projections ----------------
__global__ __launch_bounds__(256) void k_qkv(const float* __restrict__ feat,
    const float* __restrict__ Wq, const float* __restrict__ Wk, const float* __restrict__ Wv,
    float* __restrict__ fq, float* __restrict__ fk, float* __restrict__ fv) {
  int r = threadIdx.x >> 6, c = threadIdx.x & 63;
  int row = blockIdx.x*4 + r;
  const float* f = feat + row*CINCH;
  float aq=0.f, ak=0.f, av=0.f;
  #pragma unroll
  for (int k=0;k<CINCH;k++){
    float fe = f[k];
    aq = fmaf(fe, Wq[k*CO+c], aq);
    ak = fmaf(fe, Wk[k*CO+c], ak);
    av = fmaf(fe, Wv[k*CO+c], av);
  }
  fq[row*CO+c]=aq; fk[row*CO+c]=ak; fv[row*CO+c]=av;
}

// ---------------- KNN16 partial: per-part register top-16 (sorted-shift) ----------------
#define KTS 2048
__global__ __launch_bounds__(256,4) void k_knn16p(const float4* __restrict__ qp,
    const float4* __restrict__ cp, int clen,
    float* __restrict__ psv, int* __restrict__ psi) {
  __shared__ float4 tile[KTS];
  int q = blockIdx.x*256 + threadIdx.x;
  int part = blockIdx.y;
  int nspl = gridDim.y;
  int c0 = part*clen;
  float4 tq = qp[q];
  float qx=tq.x, qy=tq.y, qz=tq.z;
  float v[KK]; int id[KK];
  #pragma unroll
  for (int k=0;k<KK;k++){ v[k]=3.4e38f; id[k]=0x7fffffff; }
  for (int base=c0; base<c0+clen; base+=KTS){
    __syncthreads();
    for (int tt=threadIdx.x;tt<KTS;tt+=256) tile[tt]=cp[base+tt];
    __syncthreads();
    for (int j=0;j<KTS;j++){
      float4 cpt=tile[j];
      float dot = qx*cpt.x + qy*cpt.y + qz*cpt.z;
      float s = fmaf(-2.f,dot,cpt.w);
      if (s < v[KK-1]) {             // strict: equal value stays out (earlier index wins)
        int gj = base+j;
        #pragma unroll
        for (int k=KK-1;k>=1;--k){
          bool sh = s < v[k-1];
          bool pl = s < v[k];        // old v[k]
          float nv = sh ? v[k-1] : (pl ? s  : v[k]);
          int   ni = sh ? id[k-1] : (pl ? gj : id[k]);
          v[k]=nv; id[k]=ni;
        }
        if (s < v[0]){ v[0]=s; id[0]=gj; }
      }
    }
  }
  size_t o = ((size_t)q*nspl + part)*KK;
  #pragma unroll
  for (int k=0;k<KK;k++){ psv[o+k]=v[k]; psi[o+k]=id[k]; }
}

// ---------------- merge NS sorted 16-lists -> top 16 (lexicographic (v,idx)) ----------------
template<int NS>
__global__ __launch_bounds__(256,4) void k_merge(const float* __restrict__ psv,
    const int* __restrict__ psi, int* __restrict__ oidx) {
  int q = blockIdx.x*256 + threadIdx.x;
  const float* pv = psv + (size_t)q*NS*KK;
  const int*   pi = psi + (size_t)q*NS*KK;
  int pos[NS]; float hv[NS]; int hi[NS];
  #pragma unroll
  for (int p=0;p<NS;p++){ pos[p]=0; hv[p]=pv[p*KK]; hi[p]=pi[p*KK]; }
  #pragma unroll
  for (int k=0;k<KK;k++){
    int best=0; float bv=hv[0]; int bi=hi[0];
    #pragma unroll
    for (int p=1;p<NS;p++){
      bool g=(hv[p]<bv)||((hv[p]==bv)&&(hi[p]<bi));
      if (g){ bv=hv[p]; bi=hi[p]; best=p; }
    }
    oidx[q*KK+k]=bi;
    #pragma unroll
    for (int p=0;p<NS;p++) if (best==p){
      pos[p]++;
      bool ok = pos[p]<KK;
      hv[p] = ok ? pv[p*KK+pos[p]] : 3.4e38f;
      hi[p] = ok ? pi[p*KK+pos[p]] : 0x7fffffff;
    }
  }
}

// ---------------- rel = p_i - p_knn ; y = rel @ Wp1 ; stats ----------------
__global__ __launch_bounds__(256) void k_rel(const float4* __restrict__ pts4, const int* __restrict__ kidx,
    const float* __restrict__ Wp1, float* __restrict__ y, float* __restrict__ st) {
  int r = blockIdx.x*256 + threadIdx.x;
  int i = r>>4;
  int j = kidx[r];
  float4 pi=pts4[i], pj=pts4[j];
  float rx=pi.x-pj.x, ry=pi.y-pj.y, rz=pi.z-pj.z;
  float s[3], sq[3];
  #pragma unroll
  for (int c=0;c<3;c++){
    float yc = rx*Wp1[c] + ry*Wp1[3+c] + rz*Wp1[6+c];
    y[r*3+c]=yc; s[c]=yc; sq[c]=yc*yc;
  }
  #pragma unroll
  for (int c=0;c<3;c++){
    float a=s[c], b=sq[c];
    #pragma unroll
    for (int o=32;o;o>>=1){ a+=__shfl_down(a,o); b+=__shfl_down(b,o); }
    if ((threadIdx.x&63)==0){ atomicAdd(&st[c],a); atomicAdd(&st[3+c],b); }
  }
}

// ---------------- yn = relu(bn(y)) ----------------
__global__ __launch_bounds__(256) void k_yn(const float* __restrict__ y, const float* __restrict__ st,
    const float* __restrict__ gp, const float* __restrict__ bp, float* __restrict__ yn) {
  int r = blockIdx.x*256 + threadIdx.x;
  const float invn = 1.f/(float)(NP*KK);
  #pragma unroll
  for (int c=0;c<3;c++){
    float m = st[c]*invn;
    float var = st[3+c]*invn - m*m;
    float rs = 1.f/sqrtf(var+1e-5f);
    float t = (y[r*3+c]-m)*rs;
    t = fmaf(t, gp[c], bp[c]);
    yn[r*3+c] = fmaxf(t,0.f);
  }
}

// ---------------- stats of x = fq - fk[knn] + rpe ----------------
__global__ __launch_bounds__(256) void k_xstats(const float* __restrict__ fq, const float* __restrict__ fk,
    const int* __restrict__ kidx, const float* __restrict__ yn, const float* __restrict__ Wp2,
    float* __restrict__ st) {
  __shared__ float red[2][4][64];
  int w=threadIdx.x>>6, c=threadIdx.x&63;
  float w0=Wp2[c], w1=Wp2[64+c], w2=Wp2[128+c];
  float s=0.f,sq=0.f;
  int row0 = blockIdx.x*256 + w*64;
  for (int t=0;t<64;t++){
    int r=row0+t; int p=r>>4; int j=kidx[r];
    float y0=yn[r*3], y1=yn[r*3+1], y2=yn[r*3+2];
    float x = fq[p*CO+c]-fk[j*CO+c]+(y0*w0+y1*w1+y2*w2);
    s+=x; sq=fmaf(x,x,sq);
  }
  red[0][w][c]=s; red[1][w][c]=sq;
  __syncthreads();
  if (w==0){
    float a=red[0][0][c]+red[0][1][c]+red[0][2][c]+red[0][3][c];
    float b=red[1][0][c]+red[1][1][c]+red[1][2][c]+red[1][3][c];
    atomicAdd(&st[c],a); atomicAdd(&st[64+c],b);
  }
}

// ---------------- stats of x1 = relu(bn1(x)) @ Wa1 ----------------
__global__ __launch_bounds__(256) void k_x1stats(const float* __restrict__ fq,const float* __restrict__ fk,
    const int* __restrict__ kidx, const float* __restrict__ yn, const float* __restrict__ Wp2,
    const float* __restrict__ Wa1, const float* __restrict__ ga1, const float* __restrict__ ba1,
    const float* __restrict__ stx, float* __restrict__ st1) {
  __shared__ float wa1[4096];
  __shared__ float red[2][4][64];
  for (int t=threadIdx.x;t<4096;t+=256) wa1[t]=Wa1[t];
  int w=threadIdx.x>>6, c=threadIdx.x&63;
  const float invn=1.f/(float)(NP*KK);
  float m1=stx[c]*invn; float vv=stx[64+c]*invn-m1*m1; float rs1=1.f/sqrtf(vv+1e-5f);
  float g1=ga1[c], bb1=ba1[c];
  float w0=Wp2[c],w1=Wp2[64+c],w2=Wp2[128+c];
  __syncthreads();
  float s=0.f,sq=0.f;
  int row0 = blockIdx.x*128 + w*32;
  for (int t=0;t<32;t++){
    int r=row0+t; int p=r>>4; int j=kidx[r];
    float y0=yn[r*3],y1=yn[r*3+1],y2=yn[r*3+2];
    float x = fq[p*CO+c]-fk[j*CO+c]+(y0*w0+y1*w1+y2*w2);
    float tt=(x-m1)*rs1; tt=fmaxf(fmaf(tt,g1,bb1),0.f);
    float x1 = waveGemm64(tt, wa1, c);
    s += x1; sq = fmaf(x1,x1,sq);
  }
  red[0][w][c]=s; red[1][w][c]=sq;
  __syncthreads();
  if (w==0){
    float a=red[0][0][c]+red[0][1][c]+red[0][2][c]+red[0][3][c];
    float b=red[1][0][c]+red[1][1][c]+red[1][2][c]+red[1][3][c];
    atomicAdd(&st1[c],a); atomicAdd(&st1[64+c],b);
  }
}

// ---------------- attention: x2, softmax over K, skip ----------------
__global__ __launch_bounds__(256) void k_attn(const float* __restrict__ fq,const float* __restrict__ fk,
    const float* __restrict__ fv,const int* __restrict__ kidx,const float* __restrict__ yn,
    const float* __restrict__ Wp2,const float* __restrict__ Wa1,const float* __restrict__ Wa2,
    const float* __restrict__ ga1,const float* __restrict__ ba1,const float* __restrict__ ga2,
    const float* __restrict__ ba2,const float* __restrict__ b_a2,
    const float* __restrict__ stx,const float* __restrict__ st1, float* __restrict__ skip) {
  __shared__ float wa1[4096], wa2[4096];
  __shared__ float sc[4][16][64];
  for (int t=threadIdx.x;t<4096;t+=256){ wa1[t]=Wa1[t]; wa2[t]=Wa2[t]; }
  int w=threadIdx.x>>6, c=threadIdx.x&63;
  int p = blockIdx.x*4 + w;
  const float invn = 1.f/(float)(NP*KK);
  float m1=stx[c]*invn; float va=stx[64+c]*invn-m1*m1; float rs1=1.f/sqrtf(va+1e-5f);
  float m2=st1[c]*invn; float vb=st1[64+c]*invn-m2*m2; float rs2=1.f/sqrtf(vb+1e-5f);
  float g1=ga1[c], bb1=ba1[c], g2=ga2[c], bb2=ba2[c], bc=b_a2[c];
  float w0=Wp2[c], w1=Wp2[64+c], w2=Wp2[128+c];
  float fqv = fq[p*CO+c];
  __syncthreads();
  for (int k=0;k<16;k++){
    int r=p*16+k; int j=kidx[r];
    float y0=yn[r*3],y1=yn[r*3+1],y2=yn[r*3+2];
    float x = fqv - fk[j*CO+c] + (y0*w0+y1*w1+y2*w2);
    float t1 = (x-m1)*rs1; t1 = fmaxf(fmaf(t1,g1,bb1),0.f);
    float x1 = waveGemm64(t1, wa1, c);
    float t2 = (x1-m2)*rs2; t2 = fmaxf(fmaf(t2,g2,bb2),0.f);
    float x2 = waveGemm64(t2, wa2, c) + bc;
    sc[w][k][c] = x2;
  }
  float mx = sc[w][0][c];
  #pragma unroll
  for (int k=1;k<16;k++) mx = fmaxf(mx, sc[w][k][c]);
  float sum=0.f;
  for (int k=0;k<16;k++){ float e=expf(sc[w][k][c]-mx); sc[w][k][c]=e; sum+=e; }
  float acc=0.f;
  for (int k=0;k<16;k++){
    int r=p*16+k; int j=kidx[r];
    float y0=yn[r*3],y1=yn[r*3+1],y2=yn[r*3+2];
    float rpe = y0*w0+y1*w1+y2*w2;
    acc = fmaf(sc[w][k][c], fv[j*CO+c]+rpe, acc);
  }
  skip[p*CO+c] = acc/sum;
}

// ---------------- FPS v7: r1 structure, arrays forced into registers ----------------
// Single variable change vs r6: px/py/pz/dm as NAMED SCALARS (SROA-proof) +
// (1024,2) so the RA has 256 VGPRs. Hypothesis: r1/r6's 2.19us/step was
// scratch-spill traffic (VGPR_Count=48 with 64+ live floats); registers cut
// the step to the issue+chain floor.
#define FPS_DECL(i) float px##i,py##i,pz##i,dm##i;
#define FPS_LOAD(i) { float4 p = pts4[t*16+i]; px##i=p.x; py##i=p.y; pz##i=p.z; dm##i=1e10f; }
#define FPS_UPD(i)  { float dx=px##i-fx, dy=py##i-fy, dz=pz##i-fz; \
                      float q0=dx*dx, q1=dy*dy, q2=dz*dz; \
                      float d=(q0+q1)+q2; \
                      float nd=fminf(dm##i,d); dm##i=nd; \
                      bool g = nd>bv; bv=g?nd:bv; bi=g?(base+i):bi; }
__global__ __launch_bounds__(1024,2) void k_fps(const float4* __restrict__ pts4,
    int* __restrict__ sidx) {
  #pragma clang fp contract(off)
  __shared__ float rbv[16];
  __shared__ int rbi[16];
  int t = threadIdx.x;
  int base = t*16;
  FPS_DECL(0)  FPS_DECL(1)  FPS_DECL(2)  FPS_DECL(3)
  FPS_DECL(4)  FPS_DECL(5)  FPS_DECL(6)  FPS_DECL(7)
  FPS_DECL(8)  FPS_DECL(9)  FPS_DECL(10) FPS_DECL(11)
  FPS_DECL(12) FPS_DECL(13) FPS_DECL(14) FPS_DECL(15)
  FPS_LOAD(0)  FPS_LOAD(1)  FPS_LOAD(2)  FPS_LOAD(3)
  FPS_LOAD(4)  FPS_LOAD(5)  FPS_LOAD(6)  FPS_LOAD(7)
  FPS_LOAD(8)  FPS_LOAD(9)  FPS_LOAD(10) FPS_LOAD(11)
  FPS_LOAD(12) FPS_LOAD(13) FPS_LOAD(14) FPS_LOAD(15)
  int far = 0;
  float4 f0 = pts4[0];
  float fx=f0.x, fy=f0.y, fz=f0.z;
  for (int s=0;s<SP;s++){
    if (t==0) sidx[s]=far;
    float bv=-1.f; int bi=0;
    FPS_UPD(0)  FPS_UPD(1)  FPS_UPD(2)  FPS_UPD(3)
    FPS_UPD(4)  FPS_UPD(5)  FPS_UPD(6)  FPS_UPD(7)
    FPS_UPD(8)  FPS_UPD(9)  FPS_UPD(10) FPS_UPD(11)
    FPS_UPD(12) FPS_UPD(13) FPS_UPD(14) FPS_UPD(15)
    #pragma unroll
    for (int o=1;o<64;o<<=1){
      float ov=__shfl_xor(bv,o); int oi=__shfl_xor(bi,o);
      bool g = (ov>bv)||((ov==bv)&&(oi<bi));
      bv=g?ov:bv; bi=g?oi:bi;
    }
    __syncthreads();
    if ((t&63)==0){ rbv[t>>6]=bv; rbi[t>>6]=bi; }
    __syncthreads();
    float cv=rbv[t&15]; int ci=rbi[t&15];
    #pragma unroll
    for (int o=1;o<16;o<<=1){
      float ov=__shfl_xor(cv,o); int oi=__shfl_xor(ci,o);
      bool g=(ov>cv)||((ov==cv)&&(oi<ci));
      cv=g?ov:cv; ci=g?oi:ci;
    }
    far = ci;
    float4 fp = pts4[far];
    fx=fp.x; fy=fp.y; fz=fp.z;
  }
}

// ---------------- gather sampled points ----------------
__global__ __launch_bounds__(256) void k_gather(const float4* __restrict__ pts4, const int* __restrict__ sidx,
    float4* __restrict__ spts4) {
  int q = blockIdx.x*256 + threadIdx.x;
  spts4[q] = pts4[sidx[q]];
}

// ---------------- TransitionDown pass 1 ----------------
__global__ __launch_bounds__(256) void k_d1(const float* __restrict__ skip, const int* __restrict__ idx2,
    const float* __restrict__ Wd1, float* __restrict__ t1, float* __restrict__ st) {
  __shared__ float wl[4096];
  __shared__ float red[2][4][64];
  for (int t=threadIdx.x;t<4096;t+=256) wl[t]=Wd1[t];
  int w=threadIdx.x>>6, c=threadIdx.x&63;
  __syncthreads();
  float s=0.f,sq=0.f;
  int row0 = blockIdx.x*64 + w*16;
  for (int t=0;t<16;t++){
    int r=row0+t; int src=idx2[r];
    float kf = skip[src*CO+c];
    float o = waveGemm64(kf, wl, c);
    t1[r*CO+c]=o; s+=o; sq=fmaf(o,o,sq);
  }
  red[0][w][c]=s; red[1][w][c]=sq;
  __syncthreads();
  if (w==0){
    float a=red[0][0][c]+red[0][1][c]+red[0][2][c]+red[0][3][c];
    float b=red[1][0][c]+red[1][1][c]+red[1][2][c]+red[1][3][c];
    atomicAdd(&st[c],a); atomicAdd(&st[64+c],b);
  }
}

// ---------------- TransitionDown pass 2 ----------------
__global__ __launch_bounds__(256) void k_d2(const float* __restrict__ t1in, const float* __restrict__ stin,
    const float* __restrict__ gd1, const float* __restrict__ bd1, const float* __restrict__ Wd2,
    float* __restrict__ t2, float* __restrict__ st) {
  __shared__ float wl[4096];
  __shared__ float red[2][4][64];
  for (int t=threadIdx.x;t<4096;t+=256) wl[t]=Wd2[t];
  int w=threadIdx.x>>6, c=threadIdx.x&63;
  const float invn = 1.f/(float)(SP*KK);
  float m=stin[c]*invn; float va=stin[64+c]*invn-m*m; float rs=1.f/sqrtf(va+1e-5f);
  float g=gd1[c], bb=bd1[c];
  __syncthreads();
  float s=0.f,sq=0.f;
  int row0 = blockIdx.x*64 + w*16;
  for (int t=0;t<16;t++){
    int r=row0+t;
    float h = (t1in[r*CO+c]-m)*rs; h = fmaxf(fmaf(h,g,bb),0.f);
    float o = waveGemm64(h, wl, c);
    t2[r*CO+c]=o; s+=o; sq=fmaf(o,o,sq);
  }
  red[0][w][c]=s; red[1][w][c]=sq;
  __syncthreads();
  if (w==0){
    float a=red[0][0][c]+red[0][1][c]+red[0][2][c]+red[0][3][c];
    float b=red[1][0][c]+red[1][1][c]+red[1][2][c]+red[1][3][c];
    atomicAdd(&st[c],a); atomicAdd(&st[64+c],b);
  }
}

// ---------------- down_f = max_k relu(bn(t2)); df = down_f @ Wdn + bdn ----------------
__global__ __launch_bounds__(256) void k_downf(const float* __restrict__ t2, const float* __restrict__ stin,
    const float* __restrict__ gd2, const float* __restrict__ bd2, const float* __restrict__ Wdn,
    const float* __restrict__ bdn, float* __restrict__ df) {
  __shared__ float wl[4096];
  for (int t=threadIdx.x;t<4096;t+=256) wl[t]=Wdn[t];
  int w=threadIdx.x>>6, c=threadIdx.x&63;
  int srow = blockIdx.x*4 + w;
  const float invn = 1.f/(float)(SP*KK);
  float m=stin[c]*invn; float va=stin[64+c]*invn-m*m; float rs=1.f/sqrtf(va+1e-5f);
  float g=gd2[c], bb=bd2[c];
  __syncthreads();
  float mx=-3.4e38f;
  for (int k=0;k<16;k++){
    float h=(t2[(srow*16+k)*CO+c]-m)*rs; h=fmaxf(fmaf(h,g,bb),0.f);
    mx=fmaxf(mx,h);
  }
  float o = waveGemm64(mx, wl, c) + bdn[c];
  df[srow*CO+c]=o;
}

// ---------------- KNN k=3 with distances ----------------
__global__ __launch_bounds__(256,4) void k_knn3(const float4* __restrict__ qp, const float4* __restrict__ cp,
    int* __restrict__ idx3, float* __restrict__ d3) {
  __shared__ float4 tile[2048];
  int q = blockIdx.x*256 + threadIdx.x;
  float4 Q = qp[q];
  float v0=3.4e38f,v1=3.4e38f,v2=3.4e38f;
  int i0=0x7fffffff,i1=0x7fffffff,i2=0x7fffffff;
  for (int base=0;base<SP;base+=2048){
    __syncthreads();
    for (int tt=threadIdx.x;tt<2048;tt+=256) tile[tt]=cp[base+tt];
    __syncthreads();
    for (int j=0;j<2048;j++){
      float4 cpt = tile[j];
      float dot = Q.x*cpt.x + Q.y*cpt.y + Q.z*cpt.z;
      float d = fmaf(-2.f, dot, Q.w) + cpt.w;
      if (d < v2){
        int gj = base+j;
        bool s2 = d < v1;             // shift v1 -> v2 ?
        bool s1 = d < v0;             // shift v0 -> v1 ?
        v2 = s2 ? v1 : d;  i2 = s2 ? i1 : gj;
        v1 = s2 ? (s1 ? v0 : d) : v1; i1 = s2 ? (s1 ? i0 : gj) : i1;
        v0 = s1 ? d : v0;  i0 = s1 ? gj : i0;
      }
    }
  }
  idx3[q*3]=i0; idx3[q*3+1]=i1; idx3[q*3+2]=i2;
  d3[q*3]=v0; d3[q*3+1]=v1; d3[q*3+2]=v2;
}

// ---------------- final: interp + skip @ Wup + bup ----------------
__global__ __launch_bounds__(256) void k_out(const float* __restrict__ df, const int* __restrict__ idx3,
    const float* __restrict__ d3, const float* __restrict__ skip, const float* __restrict__ Wup,
    const float* __restrict__ bup, float* __restrict__ out) {
  __shared__ float wl[4096];
  for (int t=threadIdx.x;t<4096;t+=256) wl[t]=Wup[t];
  int w=threadIdx.x>>6, c=threadIdx.x&63;
  int i = blockIdx.x*4 + w;
  __syncthreads();
  int j0=idx3[i*3], j1=idx3[i*3+1], j2=idx3[i*3+2];
  float e0=d3[i*3], e1=d3[i*3+1], e2=d3[i*3+2];
  float r0=1.f/(e0+1e-8f), r1=1.f/(e1+1e-8f), r2=1.f/(e2+1e-8f);
  float sm=(r0+r1)+r2;
  float w0=r0/sm, w1=r1/sm, w2=r2/sm;
  float interp = (w0*df[j0*CO+c] + w1*df[j1*CO+c]) + w2*df[j2*CO+c];
  float sk = skip[i*CO+c];
  float up = waveGemm64(sk, wl, c);
  out[i*CO+c] = (interp + up) + bup[c];
}

// ---------------- launch ----------------
extern "C" void kernel_launch(void* const* d_in, const int* in_sizes, int n_in,
                              void* d_out, int out_size, void* d_ws, size_t ws_size,
                              hipStream_t stream) {
  (void)in_sizes; (void)n_in; (void)out_size; (void)ws_size;
  const float* points   = (const float*)d_in[0];
  const float* features = (const float*)d_in[1];
  const float* Wq  = (const float*)d_in[2];
  const float* Wk  = (const float*)d_in[3];
  const float* Wv  = (const float*)d_in[4];
  const float* ga1 = (const float*)d_in[5];
  const float* ba1 = (const float*)d_in[6];
  const float* Wa1 = (const float*)d_in[7];
  const float* ga2 = (const float*)d_in[8];
  const float* ba2 = (const float*)d_in[9];
  const float* Wa2 = (const float*)d_in[10];
  const float* b_a2= (const float*)d_in[11];
  const float* Wp1 = (const float*)d_in[12];
  const float* gp  = (const float*)d_in[13];
  const float* bp  = (const float*)d_in[14];
  const float* Wp2 = (const float*)d_in[15];
  const float* Wd1 = (const float*)d_in[16];
  const float* gd1 = (const float*)d_in[17];
  const float* bd1 = (const float*)d_in[18];
  const float* Wd2 = (const float*)d_in[19];
  const float* gd2 = (const float*)d_in[20];
  const float* bd2 = (const float*)d_in[21];
  const float* Wup = (const float*)d_in[22];
  const float* bup = (const float*)d_in[23];
  const float* Wdn = (const float*)d_in[24];
  const float* bdn = (const float*)d_in[25];
  float* out = (float*)d_out;

  char* wp = (char*)d_ws;
  auto carve = [&](size_t bytes)->char* { char* p = wp; wp += (bytes + 255) & ~(size_t)255; return p; };
  float4* pts4  = (float4*)carve((size_t)NP*16);
  float*  fq    = (float*) carve((size_t)NP*CO*4);
  float*  fk    = (float*) carve((size_t)NP*CO*4);
  float*  fv    = (float*) carve((size_t)NP*CO*4);
  int*    kidx  = (int*)   carve((size_t)NP*KK*4);
  float*  y     = (float*) carve((size_t)NP*KK*3*4);
  float*  yn    = (float*) carve((size_t)NP*KK*3*4);
  float*  skip  = (float*) carve((size_t)NP*CO*4);
  int*    sidx  = (int*)   carve((size_t)SP*4);
  float4* spts4 = (float4*)carve((size_t)SP*16);
  int*    idx2  = (int*)   carve((size_t)SP*KK*4);
  float*  t1    = (float*) carve((size_t)SP*KK*CO*4);   // 16MB; split bufs alias head
  float*  t2    = (float*) carve((size_t)SP*KK*CO*4);   // 16MB
  float*  df    = (float*) carve((size_t)SP*CO*4);
  int*    idx3  = (int*)   carve((size_t)NP*3*4);
  float*  d3    = (float*) carve((size_t)NP*3*4);
  float*  stats = (float*) carve(4096);                 // zeroed each launch
  float* stRel = stats;        // 6 floats
  float* stX   = stats + 8;    // 128
  float* stX1  = stats + 136;  // 128
  float* stD1  = stats + 264;  // 128
  float* stD2  = stats + 392;  // 128
  // KNN split buffers alias t1/t2 (consumed by merges before k_d1/k_d2 write them)
  float* psvNP = t1;                         // 16384*4*16*4B = 4MB
  int*   psiNP = (int*)(t1 + (size_t)NP*4*KK);
  float* psvSP = t2;                         // 4096*8*16*4B = 2MB
  int*   psiSP = (int*)(t2 + (size_t)SP*8*KK);

  hipMemsetAsync(stats, 0, 4096, stream);

  k_pts4   <<<NP/256, 256, 0, stream>>>(points, pts4);
  // transformer layer
  k_qkv    <<<NP/4,   256, 0, stream>>>(features, Wq, Wk, Wv, fq, fk, fv);
  k_knn16p <<<dim3(NP/256,4), 256, 0, stream>>>(pts4, pts4, NP/4, psvNP, psiNP);
  k_merge<4><<<NP/256, 256, 0, stream>>>(psvNP, psiNP, kidx);
  k_rel    <<<NP*KK/256, 256, 0, stream>>>(pts4, kidx, Wp1, y, stRel);
  k_yn     <<<NP*KK/256, 256, 0, stream>>>(y, stRel, gp, bp, yn);
  k_xstats <<<NP*KK/256, 256, 0, stream>>>(fq, fk, kidx, yn, Wp2, stX);
  k_x1stats<<<NP*KK/128, 256, 0, stream>>>(fq, fk, kidx, yn, Wp2, Wa1, ga1, ba1, stX, stX1);
  k_attn   <<<NP/4,   256, 0, stream>>>(fq, fk, fv, kidx, yn, Wp2, Wa1, Wa2, ga1, ba1, ga2, ba2, b_a2, stX, stX1, skip);
  // down / up
  k_fps    <<<1,     1024, 0, stream>>>(pts4, sidx);
  k_gather <<<SP/256, 256, 0, stream>>>(pts4, sidx, spts4);
  k_knn16p <<<dim3(SP/256,8), 256, 0, stream>>>(spts4, pts4, NP/8, psvSP, psiSP);
  k_merge<8><<<SP/256, 256, 0, stream>>>(psvSP, psiSP, idx2);
  k_d1     <<<SP*KK/64, 256, 0, stream>>>(skip, idx2, Wd1, t1, stD1);
  k_d2     <<<SP*KK/64, 256, 0, stream>>>(t1, stD1, gd1, bd1, Wd2, t2, stD2);
  k_downf  <<<SP/4,   256, 0, stream>>>(t2, stD2, gd2, bd2, Wdn, bdn, df);
  k_knn3   <<<NP/256, 256, 0, stream>>>(pts4, spts4, idx3, d3);
  k_out    <<<NP/4,   256, 0, stream>>>(df, idx3, d3, skip, Wup, bup, out);
}